// Round 12
// baseline (965.447 us; speedup 1.0000x reference)
//
#include <hip/hip_runtime.h>
#include <stdint.h>

#define Dd 16
#define Hh 64
#define Ww 64
#define NACT 40000
#define NVb 20000
#define KFORE 10000
#define EPSf 0.001f

typedef __attribute__((ext_vector_type(8))) short short8;   // 8 bf16 (4 VGPR)
typedef __attribute__((ext_vector_type(4))) float f32x4;
typedef __attribute__((ext_vector_type(4))) unsigned short us4;

static __device__ __forceinline__ uint32_t f2sort(float f) {
    uint32_t u = __float_as_uint(f);
    return (u & 0x80000000u) ? ~u : (u | 0x80000000u);
}

// round-to-nearest-even f32 -> bf16 bits (inputs finite)
static __device__ __forceinline__ unsigned short f2b(float f) {
    uint32_t u = __float_as_uint(f);
    return (unsigned short)((u + 0x7FFFu + ((u >> 16) & 1u)) >> 16);
}

// bijective XCD-contiguous remap (m204)
static __device__ __forceinline__ int xcd_swz(int orig, int nwg) {
    int xcd = orig & 7, idx = orig >> 3;
    int q = nwg >> 3, r = nwg & 7;
    int base = xcd < r ? xcd * (q + 1) : r * (q + 1) + (xcd - r) * q;
    return base + idx;
}

// ---------------- scatter features to dense grid ----------------
__global__ void __launch_bounds__(256) k_scatter(const float* __restrict__ feat,
                                                 const int* __restrict__ coords,
                                                 float* __restrict__ dense16,
                                                 uint8_t* __restrict__ active,
                                                 uint8_t* __restrict__ new_act) {
    int i = blockIdx.x * 256 + threadIdx.x;
    if (i >= NACT) return;
    int b = coords[i * 4 + 0], z = coords[i * 4 + 1], y = coords[i * 4 + 2], x = coords[i * 4 + 3];
    int pos = ((b * Dd + z) * Hh + y) * Ww + x;
    active[pos] = 1;
    new_act[pos] = 1;
    const float4* f4 = (const float4*)(feat + (size_t)i * 16);
    float4* d4 = (float4*)(dense16 + (size_t)pos * 16);
    d4[0] = f4[0]; d4[1] = f4[1]; d4[2] = f4[2]; d4[3] = f4[3];
}

// ---------------- parallel ordered compaction: count -> scan -> emit ----------------
__global__ void __launch_bounds__(256) k_cnt(const uint8_t* __restrict__ mask,
                                             int* __restrict__ bcnt) {
    __shared__ int s[256];
    const int i = blockIdx.x * 256 + threadIdx.x;
    s[threadIdx.x] = mask[i] ? 1 : 0;
    __syncthreads();
    for (int off = 128; off > 0; off >>= 1) {
        if (threadIdx.x < off) s[threadIdx.x] += s[threadIdx.x + off];
        __syncthreads();
    }
    if (threadIdx.x == 0) bcnt[blockIdx.x] = s[0];
}

__global__ void __launch_bounds__(512) k_scan(const int* __restrict__ bcnt,
                                              int* __restrict__ boff, int* __restrict__ count) {
    __shared__ int s[512];
    const int t = threadIdx.x;
    const int v0 = bcnt[t];
    s[t] = v0;
    __syncthreads();
    for (int off = 1; off < 512; off <<= 1) {
        int v = s[t];
        if (t >= off) v += s[t - off];
        __syncthreads();
        s[t] = v;
        __syncthreads();
    }
    boff[t] = s[t] - v0;           // exclusive prefix
    if (t == 511) *count = s[511];
}

__global__ void __launch_bounds__(256) k_emit(const uint8_t* __restrict__ mask,
                                              const int* __restrict__ boff,
                                              int* __restrict__ list) {
    __shared__ int s[256];
    const int i = blockIdx.x * 256 + threadIdx.x;
    const int pred = mask[i] ? 1 : 0;
    s[threadIdx.x] = pred;
    __syncthreads();
    for (int off = 1; off < 256; off <<= 1) {
        int v = s[threadIdx.x];
        if (threadIdx.x >= off) v += s[threadIdx.x - off];
        __syncthreads();
        s[threadIdx.x] = v;
        __syncthreads();
    }
    if (pred) list[boff[blockIdx.x] + s[threadIdx.x] - 1] = i;
}

// ---------------- conv1 parts: 3 tap-parts x all 32 ch -> partial[tp][c][i] ----------------
__global__ void __launch_bounds__(256) k_conv1p(const int* __restrict__ list,
        const float* __restrict__ dense16, const float* __restrict__ w1,
        float* __restrict__ pbuf) {
    const int gb = xcd_swz(blockIdx.x, 157 * 3);
    const int chunk = gb / 3, tp = gb % 3;
    const int i = chunk * 256 + threadIdx.x;
    if (i >= NACT) return;
    const int pos = list[i];
    const int z = (pos >> 12) & 15, y = (pos >> 6) & 63, x = pos & 63;
    float acc[32];
    #pragma unroll
    for (int c = 0; c < 32; ++c) acc[c] = 0.f;
    const int dz = tp - 1;
    if ((unsigned)(z + dz) < Dd) {
        for (int tt = 0; tt < 9; ++tt) {
            const int dy = tt / 3 - 1, dx = tt % 3 - 1;
            if (!((unsigned)(y + dy) < Hh && (unsigned)(x + dx) < Ww)) continue;
            const float* row = dense16 + (size_t)(pos + dz * 4096 + dy * 64 + dx) * 16;
            const float* wt = w1 + (tp * 9 + tt) * 512;
            #pragma unroll
            for (int k4 = 0; k4 < 4; ++k4) {
                float4 xv = *(const float4*)(row + k4 * 4);
                float xs[4] = {xv.x, xv.y, xv.z, xv.w};
                #pragma unroll
                for (int j = 0; j < 4; ++j)
                    #pragma unroll
                    for (int c = 0; c < 32; ++c)
                        acc[c] = fmaf(xs[j], wt[(k4 * 4 + j) * 32 + c], acc[c]);
            }
        }
    }
    #pragma unroll
    for (int c = 0; c < 32; ++c) pbuf[(size_t)(tp * 32 + c) * NACT + i] = acc[c];
}

// ---------------- conv1 combine: sum 3 parts + BN + ReLU -> h1 ----------------
__global__ void __launch_bounds__(256) k_conv1c(const int* __restrict__ list,
        const float* __restrict__ pbuf,
        const float* __restrict__ g, const float* __restrict__ bta,
        const float* __restrict__ mu, const float* __restrict__ va,
        float* __restrict__ h1) {
    const int i = blockIdx.x * 256 + threadIdx.x;
    if (i >= NACT) return;
    const int pos = list[i];
    float res[32];
    #pragma unroll
    for (int c = 0; c < 32; ++c) {
        float s = pbuf[(size_t)c * NACT + i]
                + pbuf[(size_t)(32 + c) * NACT + i]
                + pbuf[(size_t)(64 + c) * NACT + i];
        const float sc = g[c] * (1.0f / sqrtf(va[c] + EPSf));
        res[c] = fmaxf(0.f, fmaf(s - mu[c], sc, bta[c]));
    }
    #pragma unroll
    for (int c4 = 0; c4 < 8; ++c4)
        *(float4*)(h1 + (size_t)pos * 32 + c4 * 4) = *(float4*)&res[c4 * 4];
}

// ---------------- conv2 parts (staged): 3 tap-parts, block=64 voxels x 4 ch-groups ----------------
// Per tap: stage 64 neighbor rows (32 f32) coalescedly into LDS (row stride 33 -> conflict-free),
// then thread (v,og) computes out-ch og*16..+15 for voxel v. Same accumulation order as before.
__global__ void __launch_bounds__(256) k_conv2p(const int* __restrict__ list,
        const float* __restrict__ h1, const float* __restrict__ w2,
        float* __restrict__ pbuf) {
    __shared__ float S[64 * 33];
    __shared__ int s_pos[64];
    const int gb = xcd_swz(blockIdx.x, 625 * 3);
    const int chunk = gb / 3, tp = gb % 3;
    const int tid = threadIdx.x;
    if (tid < 64) s_pos[tid] = list[chunk * 64 + tid];
    __syncthreads();
    const int v = tid & 63, og = tid >> 6;       // og wave-uniform
    const int cb = og * 16;
    const int sr = tid >> 3, sc = tid & 7;       // staging: rows sr, sr+32; 16B chunk sc
    const int dz = tp - 1;
    float acc[16];
    #pragma unroll
    for (int c = 0; c < 16; ++c) acc[c] = 0.f;

    for (int tt = 0; tt < 9; ++tt) {
        const int dy = tt / 3 - 1, dx = tt % 3 - 1;
        const int off = dz * 4096 + dy * 64 + dx;
        #pragma unroll
        for (int p = 0; p < 2; ++p) {
            const int r = p * 32 + sr;
            const int pos = s_pos[r];
            const int z = (pos >> 12) & 15, y = (pos >> 6) & 63, x = pos & 63;
            bool ok = (unsigned)(z + dz) < Dd && (unsigned)(y + dy) < Hh && (unsigned)(x + dx) < Ww;
            float4 val = ok ? *(const float4*)(h1 + (size_t)(pos + off) * 32 + sc * 4)
                            : (float4){0.f, 0.f, 0.f, 0.f};
            float* d = &S[r * 33 + sc * 4];
            d[0] = val.x; d[1] = val.y; d[2] = val.z; d[3] = val.w;
        }
        __syncthreads();
        const float* wt = w2 + (tp * 9 + tt) * 2048 + cb;
        const float* myrow = &S[v * 33];
        #pragma unroll 8
        for (int k = 0; k < 32; ++k) {
            const float xv = myrow[k];
            #pragma unroll
            for (int j = 0; j < 16; ++j)
                acc[j] = fmaf(xv, wt[k * 64 + j], acc[j]);
        }
        __syncthreads();
    }
    const int i = chunk * 64 + v;
    #pragma unroll
    for (int j = 0; j < 16; ++j)
        pbuf[(size_t)(tp * 64 + cb + j) * NACT + i] = acc[j];
}

// ---------------- conv2 combine: sum 3 tap-parts + BN + ReLU -> h2 (f32) + h2b (bf16) ----------------
__global__ void __launch_bounds__(256) k_conv2c(const int* __restrict__ list,
        const float* __restrict__ pbuf,
        const float* __restrict__ g, const float* __restrict__ bta,
        const float* __restrict__ mu, const float* __restrict__ va,
        float* __restrict__ h2, unsigned short* __restrict__ h2b) {
    const int i = blockIdx.x * 256 + threadIdx.x;
    if (i >= NACT) return;
    const int pos = list[i];
    float res[64];
    #pragma unroll
    for (int c = 0; c < 64; ++c) {
        float s = pbuf[(size_t)c * NACT + i]
                + pbuf[(size_t)(64 + c) * NACT + i]
                + pbuf[(size_t)(128 + c) * NACT + i];
        const float sc = g[c] * (1.0f / sqrtf(va[c] + EPSf));
        res[c] = fmaxf(0.f, fmaf(s - mu[c], sc, bta[c]));
    }
    #pragma unroll
    for (int c4 = 0; c4 < 16; ++c4)
        *(float4*)(h2 + (size_t)pos * 64 + c4 * 4) = *(float4*)&res[c4 * 4];
    #pragma unroll
    for (int c4 = 0; c4 < 16; ++c4) {
        us4 o = { f2b(res[c4 * 4]), f2b(res[c4 * 4 + 1]), f2b(res[c4 * 4 + 2]), f2b(res[c4 * 4 + 3]) };
        *(us4*)(h2b + (size_t)pos * 64 + c4 * 4) = o;
    }
}

// ---------------- imp parts (staged): 9 tap-parts, block=64 voxels x 4 ch-groups ----------------
// Per tap: stage 64 rows (64 f32) coalescedly (stride 65 -> conflict-free); thread (v,og)
// computes out-ch og*7..min(+6,26). Accumulation order identical to unstaged version.
__global__ void __launch_bounds__(256) k_impp(const int* __restrict__ list,
        const float* __restrict__ h2, const float* __restrict__ wimp,
        float* __restrict__ pbuf) {
    __shared__ float S[64 * 65];
    __shared__ int s_pos[64];
    const int gb = xcd_swz(blockIdx.x, 625 * 9);
    const int chunk = gb / 9, tp = gb % 9;
    const int tid = threadIdx.x;
    if (tid < 64) s_pos[tid] = list[chunk * 64 + tid];
    __syncthreads();
    const int v = tid & 63, og = tid >> 6;       // og wave-uniform
    const int sr = tid >> 4, sc = tid & 15;      // staging: rows sr+{0,16,32,48}; 16B chunk sc
    float acc[7];
    #pragma unroll
    for (int c = 0; c < 7; ++c) acc[c] = 0.f;

    for (int tt = 0; tt < 3; ++tt) {
        const int t = tp * 3 + tt;
        const int dz = t / 9 - 1, dy = (t / 3) % 3 - 1, dx = t % 3 - 1;
        const int off = dz * 4096 + dy * 64 + dx;
        #pragma unroll
        for (int p = 0; p < 4; ++p) {
            const int r = p * 16 + sr;
            const int pos = s_pos[r];
            const int z = (pos >> 12) & 15, y = (pos >> 6) & 63, x = pos & 63;
            bool ok = (unsigned)(z + dz) < Dd && (unsigned)(y + dy) < Hh && (unsigned)(x + dx) < Ww;
            float4 val = ok ? *(const float4*)(h2 + (size_t)(pos + off) * 64 + sc * 4)
                            : (float4){0.f, 0.f, 0.f, 0.f};
            float* d = &S[r * 65 + sc * 4];
            d[0] = val.x; d[1] = val.y; d[2] = val.z; d[3] = val.w;
        }
        __syncthreads();
        const float* wt = wimp + t * 1728;
        const float* myrow = &S[v * 65];
        #pragma unroll 8
        for (int k = 0; k < 64; ++k) {
            const float xv = myrow[k];
            #pragma unroll
            for (int j = 0; j < 7; ++j) {
                const int och = og * 7 + j;
                const int coch = och < 27 ? och : 26;   // clamp: garbage FMA, not stored
                acc[j] = fmaf(xv, wt[k * 27 + coch], acc[j]);
            }
        }
        __syncthreads();
    }
    const int i = chunk * 64 + v;
    #pragma unroll
    for (int j = 0; j < 7; ++j) {
        const int och = og * 7 + j;
        if (och < 27) pbuf[(size_t)(tp * 27 + och) * NACT + i] = acc[j];
    }
}

// ---------------- imp combine: sum 9 parts -> kernel-mask bits + voxel logit ----------------
__global__ void __launch_bounds__(256) k_impc(const float* __restrict__ pbuf,
        uint32_t* __restrict__ u_logits, uint32_t* __restrict__ kbits) {
    const int i = blockIdx.x * 256 + threadIdx.x;
    if (i >= NACT) return;
    uint32_t bits = 0;
    float logit = 0.f;
    #pragma unroll
    for (int c = 0; c < 27; ++c) {
        float s = 0.f;
        #pragma unroll
        for (int tp = 0; tp < 9; ++tp)
            s += pbuf[(size_t)(tp * 27 + c) * NACT + i];
        if (c < 26) bits |= (s >= 0.f ? 1u : 0u) << c;
        else logit = s;
    }
    kbits[i] = bits;
    u_logits[i] = f2sort(logit);
}

// ---------------- exact kth-largest ----------------
__global__ void __launch_bounds__(256) k_select(const uint32_t* __restrict__ u_all,
                                                uint32_t* __restrict__ kth_u) {
    const int b = blockIdx.x;
    const uint32_t* u = u_all + (size_t)b * NVb;
    __shared__ int hist[256];
    __shared__ int s_d, s_above;
    uint32_t prefix = 0;
    int K = KFORE;
    for (int p = 3; p >= 0; --p) {
        hist[threadIdx.x] = 0;
        __syncthreads();
        const int sh = p * 8;
        for (int i = threadIdx.x; i < NVb; i += 256) {
            uint32_t ui = u[i];
            bool cand;
            if (p == 3) cand = true;
            else cand = ((ui >> (sh + 8)) == prefix);
            if (cand) atomicAdd(&hist[(ui >> sh) & 255], 1);
        }
        __syncthreads();
        if (threadIdx.x == 0) {
            int cum = 0, d = 255;
            for (; d >= 0; --d) { cum += hist[d]; if (cum >= K) break; }
            s_d = d; s_above = cum - hist[d];
        }
        __syncthreads();
        prefix = (prefix << 8) | (uint32_t)s_d;
        K -= s_above;
        __syncthreads();
    }
    if (threadIdx.x == 0) kth_u[b] = prefix;
}

// ---------------- dilation ----------------
__global__ void __launch_bounds__(256) k_dilate(const int* __restrict__ list,
                                                const uint32_t* __restrict__ u_logits,
                                                const uint32_t* __restrict__ kbits,
                                                const uint32_t* __restrict__ kth_u,
                                                uint8_t* __restrict__ new_act) {
    int i = blockIdx.x * 256 + threadIdx.x;
    if (i >= NACT) return;
    int pos = list[i];
    int b = pos >> 16;
    if (u_logits[i] < kth_u[b]) return;
    int z = (pos >> 12) & 15, y = (pos >> 6) & 63, x = pos & 63;
    uint32_t bits = kbits[i];
    while (bits) {
        int ch = __ffs(bits) - 1;
        bits &= bits - 1;
        int l = ch + (ch >= 13 ? 1 : 0);
        int oz = l / 9 - 1, oy = (l / 3) % 3 - 1, ox = l % 3 - 1;
        int tz = z + oz, ty = y + oy, tx = x + ox;
        if (tz >= 1 && tz < Dd && ty >= 1 && ty < Hh && tx >= 1 && tx < Ww)
            new_act[((b * Dd + tz) * Hh + ty) * Ww + tx] = 1;
    }
}

// ---------------- w_focal f32 [27][64][128] -> bf16 transposed [27][128][64] ----------------
__global__ void __launch_bounds__(256) k_wcvt(const float* __restrict__ wf,
                                              unsigned short* __restrict__ wfb) {
    int i = blockIdx.x * 256 + threadIdx.x;   // 221184 total
    int t = i >> 13, r = i & 8191, n = r >> 6, k = r & 63;
    wfb[i] = f2b(wf[(t * 64 + k) * 128 + n]);
}

// ---------------- focal conv 64->128 via bf16 MFMA, depth-2 gather pipeline ----------------
// 256 thr (4 waves), 64 voxels/block; wave wv owns 32 output ch (2 N-tiles).
// As XOR-swizzled (16B-slot ^ (row&7)) -> 0 bank conflicts (measured R8/R9).
// Pipeline: at macro-iter (taps t,t+1): rA holds gather(t+2), rB holds gather(t+3).
__global__ void __launch_bounds__(256, 4) k_focal(
        const int* __restrict__ list, const int* __restrict__ count,
        const unsigned short* __restrict__ h2b, const unsigned short* __restrict__ wfb,
        const float* __restrict__ g, const float* __restrict__ bta,
        const float* __restrict__ mu, const float* __restrict__ va,
        float* __restrict__ out, const unsigned short* __restrict__ zb) {
    __shared__ __align__(16) unsigned short As[2][64 * 64];  // swizzled, no pad
    __shared__ int s_pos[64];
    const int n = *count;
    const int i0 = xcd_swz(blockIdx.x, 2048) * 64;
    if (i0 >= n) return;
    const int tid = threadIdx.x;
    const int wv = tid >> 6, lane = tid & 63;
    if (tid < 64) { int idx = i0 + tid; s_pos[tid] = idx < n ? list[idx] : -1; }
    __syncthreads();
    const int v0 = tid >> 3, c8 = tid & 7, v1 = v0 + 32;   // each thread stages rows v0, v1
    const int p0 = s_pos[v0], p1 = s_pos[v1];
    const int z0 = (p0 >> 12) & 15, y0 = (p0 >> 6) & 63, x0 = p0 & 63;
    const int z1 = (p1 >> 12) & 15, y1 = (p1 >> 6) & 63, x1 = p1 & 63;
    const int wslot = (c8 ^ (v0 & 7)) << 3;                 // v1&7 == v0&7
    const int wa0 = v0 * 64 + wslot, wa1 = v1 * 64 + wslot;
    const int hi = lane >> 4, lo = lane & 15;
    const int cb = wv * 32;

    f32x4 acc[4][2];
    #pragma unroll
    for (int mi = 0; mi < 4; ++mi)
        #pragma unroll
        for (int ni = 0; ni < 2; ++ni) acc[mi][ni] = (f32x4){0.f, 0.f, 0.f, 0.f};

    auto gather = [&](int t, short8& r0, short8& r1) {
        int dz = t / 9 - 1, dy = (t / 3) % 3 - 1, dx = t % 3 - 1;
        int off = dz * 4096 + dy * 64 + dx;
        bool ok0 = p0 >= 0 && (unsigned)(z0 + dz) < Dd && (unsigned)(y0 + dy) < Hh && (unsigned)(x0 + dx) < Ww;
        bool ok1 = p1 >= 0 && (unsigned)(z1 + dz) < Dd && (unsigned)(y1 + dy) < Hh && (unsigned)(x1 + dx) < Ww;
        r0 = *(const short8*)(ok0 ? h2b + (size_t)(p0 + off) * 64 + c8 * 8 : zb);
        r1 = *(const short8*)(ok1 ? h2b + (size_t)(p1 + off) * 64 + c8 * 8 : zb);
    };

    auto compute = [&](int t, int buf) {
        short8 bfr[2][2];
        #pragma unroll
        for (int ni = 0; ni < 2; ++ni)
            #pragma unroll
            for (int ks = 0; ks < 2; ++ks)
                bfr[ni][ks] = *(const short8*)(wfb + (size_t)t * 8192
                                + (size_t)(cb + ni * 16 + lo) * 64 + ks * 32 + hi * 8);
        #pragma unroll
        for (int ks = 0; ks < 2; ++ks) {
            const int rs = ((ks * 4 + hi) ^ (lo & 7)) << 3;
            short8 a[4];
            #pragma unroll
            for (int mi = 0; mi < 4; ++mi)
                a[mi] = *(const short8*)&As[buf][(mi * 16 + lo) * 64 + rs];
            #pragma unroll
            for (int mi = 0; mi < 4; ++mi)
                #pragma unroll
                for (int ni = 0; ni < 2; ++ni)
                    acc[mi][ni] = __builtin_amdgcn_mfma_f32_16x16x32_bf16(
                        a[mi], bfr[ni][ks], acc[mi][ni], 0, 0, 0);
        }
    };

    short8 rA0, rA1, rB0, rB1;
    // prologue: taps 0,1 -> LDS; taps 2,3 in flight in rA,rB
    gather(0, rA0, rA1);
    gather(1, rB0, rB1);
    *(short8*)&As[0][wa0] = rA0; *(short8*)&As[0][wa1] = rA1;
    *(short8*)&As[1][wa0] = rB0; *(short8*)&As[1][wa1] = rB1;
    gather(2, rA0, rA1);
    gather(3, rB0, rB1);
    __syncthreads();

    for (int t = 0; t < 26; t += 2) {
        compute(t, 0);
        __syncthreads();                       // all waves done reading As[0]
        if (t + 2 <= 26) {
            *(short8*)&As[0][wa0] = rA0;       // tap t+2 (waits its own vmcnt only)
            *(short8*)&As[0][wa1] = rA1;
            if (t + 4 <= 26) gather(t + 4, rA0, rA1);
        }
        compute(t + 1, 1);
        __syncthreads();                       // done reading As[1]; As[0] write visible
        if (t + 3 <= 26) {
            *(short8*)&As[1][wa0] = rB0;       // tap t+3
            *(short8*)&As[1][wa1] = rB1;
            if (t + 5 <= 26) gather(t + 5, rB0, rB1);
        }
        if (t + 2 > 26) break;
    }
    __syncthreads();                           // As[0]=tap 26 write visible
    compute(26, 0);

    #pragma unroll
    for (int ni = 0; ni < 2; ++ni) {
        const int ch = cb + ni * 16 + lo;
        const float s = g[ch] * (1.0f / sqrtf(va[ch] + EPSf));
        const float sh = bta[ch], mm = mu[ch];
        #pragma unroll
        for (int mi = 0; mi < 4; ++mi)
            #pragma unroll
            for (int j = 0; j < 4; ++j) {
                int vi = mi * 16 + hi * 4 + j;
                if (i0 + vi < n)
                    out[(size_t)s_pos[vi] * 128 + ch] = fmaxf(0.f, fmaf(acc[mi][ni][j] - mm, s, sh));
            }
    }
}

extern "C" void kernel_launch(void* const* d_in, const int* in_sizes, int n_in,
                              void* d_out, int out_size, void* d_ws, size_t ws_size,
                              hipStream_t stream) {
    (void)in_sizes; (void)n_in; (void)ws_size;
    const float* feat   = (const float*)d_in[0];
    const int*   coords = (const int*)d_in[1];
    const float* w1   = (const float*)d_in[2];
    const float* w2   = (const float*)d_in[3];
    const float* wimp = (const float*)d_in[4];
    const float* wf   = (const float*)d_in[5];
    const float* g1 = (const float*)d_in[6],  *b1 = (const float*)d_in[7];
    const float* m1 = (const float*)d_in[8],  *v1 = (const float*)d_in[9];
    const float* g2 = (const float*)d_in[10], *b2 = (const float*)d_in[11];
    const float* m2 = (const float*)d_in[12], *v2 = (const float*)d_in[13];
    const float* g3 = (const float*)d_in[14], *b3 = (const float*)d_in[15];
    const float* m3 = (const float*)d_in[16], *v3 = (const float*)d_in[17];

    char* ws = (char*)d_ws;
    float*    dense16  = (float*)(ws + 0);           //  8,388,608 B (wfb overlays after conv1p)
    float*    h1       = (float*)(ws + 8388608);     // 16,777,216 B (h2b overlays after conv2p)
    float*    h2       = (float*)(ws + 25165824);    // 33,554,432 B
    uint8_t*  active   = (uint8_t*)(ws + 58720256);  //    131,072 B
    uint8_t*  new_act  = (uint8_t*)(ws + 58851328);  //    131,072 B
    float*    zrow     = (float*)(ws + 58982400);    //        256 B zeros
    int*      count    = (int*)(ws + 58982656);      //        256 B
    const size_t MEMSET_BYTES = 58982912;
    uint32_t* u_logits = (uint32_t*)(ws + 58982912); //    160,000 B
    uint32_t* kbits    = (uint32_t*)(ws + 59142912); //    160,000 B (also bcnt/boff scratch)
    uint32_t* kth_u    = (uint32_t*)(ws + 59302912); //        256 B
    int*      list     = (int*)(ws + 59303168);      //    524,288 B (act list, then focal list)

    unsigned short* wfb = (unsigned short*)dense16;  // [27][128][64] bf16, after conv1p
    unsigned short* h2b = (unsigned short*)h1;       // [131072][64] bf16, after conv2p+memset
    float* pbuf = (float*)d_out;                     // partial-sum scratch (used BEFORE d_out memset)
    int* bcnt = (int*)kbits;                         // 512 ints (dead region at both compact times)
    int* boff = (int*)kbits + 512;                   // 512 ints

    hipMemsetAsync(d_ws, 0, MEMSET_BYTES, stream);

    k_scatter<<<157, 256, 0, stream>>>(feat, coords, dense16, active, new_act);
    k_cnt<<<512, 256, 0, stream>>>(active, bcnt);                       // ordered active list
    k_scan<<<1, 512, 0, stream>>>(bcnt, boff, count);
    k_emit<<<512, 256, 0, stream>>>(active, boff, list);
    k_conv1p<<<157 * 3, 256, 0, stream>>>(list, dense16, w1, pbuf);
    k_conv1c<<<157, 256, 0, stream>>>(list, pbuf, g1, b1, m1, v1, h1);
    k_wcvt<<<864, 256, 0, stream>>>(wf, wfb);                           // dense16 now dead
    k_conv2p<<<625 * 3, 256, 0, stream>>>(list, h1, w2, pbuf);
    hipMemsetAsync(h2b, 0, (size_t)131072 * 64 * 2, stream);            // h1 dead; zero inactive h2b rows
    k_conv2c<<<157, 256, 0, stream>>>(list, pbuf, g2, b2, m2, v2, h2, h2b);
    k_impp<<<625 * 9, 256, 0, stream>>>(list, h2, wimp, pbuf);
    k_impc<<<157, 256, 0, stream>>>(pbuf, u_logits, kbits);
    hipMemsetAsync(d_out, 0, (size_t)out_size * sizeof(float), stream); // scratch done; zero output
    k_select<<<2, 256, 0, stream>>>(u_logits, kth_u);
    k_dilate<<<157, 256, 0, stream>>>(list, u_logits, kbits, kth_u, new_act);
    k_cnt<<<512, 256, 0, stream>>>(new_act, bcnt);                      // focal list (kbits dead now)
    k_scan<<<1, 512, 0, stream>>>(bcnt, boff, count);
    k_emit<<<512, 256, 0, stream>>>(new_act, boff, list);
    k_focal<<<2048, 256, 0, stream>>>(list, count, h2b, wfb, g3, b3, m3, v3,
                                      (float*)d_out, (const unsigned short*)zrow);
}

// Round 13
// 542.393 us; speedup vs baseline: 1.7800x; 1.7800x over previous
//
#include <hip/hip_runtime.h>
#include <stdint.h>

#define Dd 16
#define Hh 64
#define Ww 64
#define NACT 40000
#define NVb 20000
#define KFORE 10000
#define EPSf 0.001f

typedef __attribute__((ext_vector_type(8))) short short8;   // 8 bf16 (4 VGPR)
typedef __attribute__((ext_vector_type(4))) float f32x4;
typedef __attribute__((ext_vector_type(4))) unsigned short us4;

static __device__ __forceinline__ uint32_t f2sort(float f) {
    uint32_t u = __float_as_uint(f);
    return (u & 0x80000000u) ? ~u : (u | 0x80000000u);
}

// round-to-nearest-even f32 -> bf16 bits (inputs finite)
static __device__ __forceinline__ unsigned short f2b(float f) {
    uint32_t u = __float_as_uint(f);
    return (unsigned short)((u + 0x7FFFu + ((u >> 16) & 1u)) >> 16);
}

// bijective XCD-contiguous remap (m204)
static __device__ __forceinline__ int xcd_swz(int orig, int nwg) {
    int xcd = orig & 7, idx = orig >> 3;
    int q = nwg >> 3, r = nwg & 7;
    int base = xcd < r ? xcd * (q + 1) : r * (q + 1) + (xcd - r) * q;
    return base + idx;
}

// ---------------- scatter features to dense grid ----------------
__global__ void __launch_bounds__(256) k_scatter(const float* __restrict__ feat,
                                                 const int* __restrict__ coords,
                                                 float* __restrict__ dense16,
                                                 uint8_t* __restrict__ active,
                                                 uint8_t* __restrict__ new_act) {
    int i = blockIdx.x * 256 + threadIdx.x;
    if (i >= NACT) return;
    int b = coords[i * 4 + 0], z = coords[i * 4 + 1], y = coords[i * 4 + 2], x = coords[i * 4 + 3];
    int pos = ((b * Dd + z) * Hh + y) * Ww + x;
    active[pos] = 1;
    new_act[pos] = 1;
    const float4* f4 = (const float4*)(feat + (size_t)i * 16);
    float4* d4 = (float4*)(dense16 + (size_t)pos * 16);
    d4[0] = f4[0]; d4[1] = f4[1]; d4[2] = f4[2]; d4[3] = f4[3];
}

// ---------------- parallel ordered compaction: count -> scan -> emit ----------------
__global__ void __launch_bounds__(256) k_cnt(const uint8_t* __restrict__ mask,
                                             int* __restrict__ bcnt) {
    __shared__ int s[256];
    const int i = blockIdx.x * 256 + threadIdx.x;
    s[threadIdx.x] = mask[i] ? 1 : 0;
    __syncthreads();
    for (int off = 128; off > 0; off >>= 1) {
        if (threadIdx.x < off) s[threadIdx.x] += s[threadIdx.x + off];
        __syncthreads();
    }
    if (threadIdx.x == 0) bcnt[blockIdx.x] = s[0];
}

__global__ void __launch_bounds__(512) k_scan(const int* __restrict__ bcnt,
                                              int* __restrict__ boff, int* __restrict__ count) {
    __shared__ int s[512];
    const int t = threadIdx.x;
    const int v0 = bcnt[t];
    s[t] = v0;
    __syncthreads();
    for (int off = 1; off < 512; off <<= 1) {
        int v = s[t];
        if (t >= off) v += s[t - off];
        __syncthreads();
        s[t] = v;
        __syncthreads();
    }
    boff[t] = s[t] - v0;           // exclusive prefix
    if (t == 511) *count = s[511];
}

__global__ void __launch_bounds__(256) k_emit(const uint8_t* __restrict__ mask,
                                              const int* __restrict__ boff,
                                              int* __restrict__ list) {
    __shared__ int s[256];
    const int i = blockIdx.x * 256 + threadIdx.x;
    const int pred = mask[i] ? 1 : 0;
    s[threadIdx.x] = pred;
    __syncthreads();
    for (int off = 1; off < 256; off <<= 1) {
        int v = s[threadIdx.x];
        if (threadIdx.x >= off) v += s[threadIdx.x - off];
        __syncthreads();
        s[threadIdx.x] = v;
        __syncthreads();
    }
    if (pred) list[boff[blockIdx.x] + s[threadIdx.x] - 1] = i;
}

// ---------------- conv1 parts: 3 tap-parts x 4 ch-groups (8 ch) -> partial[tp][c][i] ----------------
__global__ void __launch_bounds__(256) k_conv1p(const int* __restrict__ list,
        const float* __restrict__ dense16, const float* __restrict__ w1,
        float* __restrict__ pbuf) {
    const int gb = xcd_swz(blockIdx.x, 157 * 12);
    const int chunk = gb / 12, sub = gb % 12;
    const int tp = sub >> 2, cb = (sub & 3) * 8;
    const int i = chunk * 256 + threadIdx.x;
    if (i >= NACT) return;
    const int pos = list[i];
    const int z = (pos >> 12) & 15, y = (pos >> 6) & 63, x = pos & 63;
    float acc[8];
    #pragma unroll
    for (int c = 0; c < 8; ++c) acc[c] = 0.f;
    const int dz = tp - 1;
    if ((unsigned)(z + dz) < Dd) {
        for (int tt = 0; tt < 9; ++tt) {
            const int dy = tt / 3 - 1, dx = tt % 3 - 1;
            if (!((unsigned)(y + dy) < Hh && (unsigned)(x + dx) < Ww)) continue;
            const float* row = dense16 + (size_t)(pos + dz * 4096 + dy * 64 + dx) * 16;
            const float* wt = w1 + (tp * 9 + tt) * 512 + cb;
            #pragma unroll
            for (int k4 = 0; k4 < 4; ++k4) {
                float4 xv = *(const float4*)(row + k4 * 4);
                float xs[4] = {xv.x, xv.y, xv.z, xv.w};
                #pragma unroll
                for (int j = 0; j < 4; ++j)
                    #pragma unroll
                    for (int c = 0; c < 8; ++c)
                        acc[c] = fmaf(xs[j], wt[(k4 * 4 + j) * 32 + c], acc[c]);
            }
        }
    }
    #pragma unroll
    for (int c = 0; c < 8; ++c) pbuf[(size_t)(tp * 32 + cb + c) * NACT + i] = acc[c];
}

// ---------------- conv1 combine: sum 3 parts + BN + ReLU -> h1 ----------------
__global__ void __launch_bounds__(256) k_conv1c(const int* __restrict__ list,
        const float* __restrict__ pbuf,
        const float* __restrict__ g, const float* __restrict__ bta,
        const float* __restrict__ mu, const float* __restrict__ va,
        float* __restrict__ h1) {
    const int i = blockIdx.x * 256 + threadIdx.x;
    if (i >= NACT) return;
    const int pos = list[i];
    float res[32];
    #pragma unroll
    for (int c = 0; c < 32; ++c) {
        float s = pbuf[(size_t)c * NACT + i]
                + pbuf[(size_t)(32 + c) * NACT + i]
                + pbuf[(size_t)(64 + c) * NACT + i];
        const float sc = g[c] * (1.0f / sqrtf(va[c] + EPSf));
        res[c] = fmaxf(0.f, fmaf(s - mu[c], sc, bta[c]));
    }
    #pragma unroll
    for (int c4 = 0; c4 < 8; ++c4)
        *(float4*)(h1 + (size_t)pos * 32 + c4 * 4) = *(float4*)&res[c4 * 4];
}

// ---------------- conv2 parts: 3 tap-parts x 4 ch-groups (16 ch) -> partial[tp][c][i] ----------------
__global__ void __launch_bounds__(256) k_conv2p(const int* __restrict__ list,
        const float* __restrict__ h1, const float* __restrict__ w2,
        float* __restrict__ pbuf) {
    const int gb = xcd_swz(blockIdx.x, 157 * 12);
    const int chunk = gb / 12, sub = gb % 12;
    const int tp = sub >> 2, cb = (sub & 3) * 16;
    const int i = chunk * 256 + threadIdx.x;
    if (i >= NACT) return;
    const int pos = list[i];
    const int z = (pos >> 12) & 15, y = (pos >> 6) & 63, x = pos & 63;
    float acc[16];
    #pragma unroll
    for (int c = 0; c < 16; ++c) acc[c] = 0.f;
    const int dz = tp - 1;
    if ((unsigned)(z + dz) < Dd) {
        for (int tt = 0; tt < 9; ++tt) {
            const int dy = tt / 3 - 1, dx = tt % 3 - 1;
            if (!((unsigned)(y + dy) < Hh && (unsigned)(x + dx) < Ww)) continue;
            const float* row = h1 + (size_t)(pos + dz * 4096 + dy * 64 + dx) * 32;
            const float* wt = w2 + (tp * 9 + tt) * 2048 + cb;
            #pragma unroll
            for (int k4 = 0; k4 < 8; ++k4) {
                float4 xv = *(const float4*)(row + k4 * 4);
                float xs[4] = {xv.x, xv.y, xv.z, xv.w};
                #pragma unroll
                for (int j = 0; j < 4; ++j)
                    #pragma unroll
                    for (int c = 0; c < 16; ++c)
                        acc[c] = fmaf(xs[j], wt[(k4 * 4 + j) * 64 + c], acc[c]);
            }
        }
    }
    #pragma unroll
    for (int c = 0; c < 16; ++c) pbuf[(size_t)(tp * 64 + cb + c) * NACT + i] = acc[c];
}

// ---------------- conv2 combine: sum 3 tap-parts + BN + ReLU -> h2 (f32) + h2b (bf16) ----------------
__global__ void __launch_bounds__(256) k_conv2c(const int* __restrict__ list,
        const float* __restrict__ pbuf,
        const float* __restrict__ g, const float* __restrict__ bta,
        const float* __restrict__ mu, const float* __restrict__ va,
        float* __restrict__ h2, unsigned short* __restrict__ h2b) {
    const int i = blockIdx.x * 256 + threadIdx.x;
    if (i >= NACT) return;
    const int pos = list[i];
    float res[64];
    #pragma unroll
    for (int c = 0; c < 64; ++c) {
        float s = pbuf[(size_t)c * NACT + i]
                + pbuf[(size_t)(64 + c) * NACT + i]
                + pbuf[(size_t)(128 + c) * NACT + i];
        const float sc = g[c] * (1.0f / sqrtf(va[c] + EPSf));
        res[c] = fmaxf(0.f, fmaf(s - mu[c], sc, bta[c]));
    }
    #pragma unroll
    for (int c4 = 0; c4 < 16; ++c4)
        *(float4*)(h2 + (size_t)pos * 64 + c4 * 4) = *(float4*)&res[c4 * 4];
    #pragma unroll
    for (int c4 = 0; c4 < 16; ++c4) {
        us4 o = { f2b(res[c4 * 4]), f2b(res[c4 * 4 + 1]), f2b(res[c4 * 4 + 2]), f2b(res[c4 * 4 + 3]) };
        *(us4*)(h2b + (size_t)pos * 64 + c4 * 4) = o;
    }
}

// ---------------- imp parts: 9 tap-parts x 2 ch-halves -> partial[tp][c][i] ----------------
template<int CB, int NC>
static __device__ __forceinline__ void imp_part(int i, int pos, int tp,
        const float* __restrict__ h2, const float* __restrict__ wimp,
        float* __restrict__ pbuf) {
    const int z = (pos >> 12) & 15, y = (pos >> 6) & 63, x = pos & 63;
    float acc[NC];
    #pragma unroll
    for (int c = 0; c < NC; ++c) acc[c] = 0.f;
    for (int tt = 0; tt < 3; ++tt) {
        const int t = tp * 3 + tt;
        const int dz = t / 9 - 1, dy = (t / 3) % 3 - 1, dx = t % 3 - 1;
        if (!((unsigned)(z + dz) < Dd && (unsigned)(y + dy) < Hh && (unsigned)(x + dx) < Ww)) continue;
        const float* row = h2 + (size_t)(pos + dz * 4096 + dy * 64 + dx) * 64;
        const float* wt = wimp + t * 1728 + CB;
        #pragma unroll
        for (int k4 = 0; k4 < 16; ++k4) {
            float4 xv = *(const float4*)(row + k4 * 4);
            float xs[4] = {xv.x, xv.y, xv.z, xv.w};
            #pragma unroll
            for (int j = 0; j < 4; ++j)
                #pragma unroll
                for (int c = 0; c < NC; ++c)
                    acc[c] = fmaf(xs[j], wt[(k4 * 4 + j) * 27 + c], acc[c]);
        }
    }
    #pragma unroll
    for (int c = 0; c < NC; ++c) pbuf[(size_t)(tp * 27 + CB + c) * NACT + i] = acc[c];
}

__global__ void __launch_bounds__(256) k_impp(const int* __restrict__ list,
        const float* __restrict__ h2, const float* __restrict__ wimp,
        float* __restrict__ pbuf) {
    const int gb = xcd_swz(blockIdx.x, 157 * 18);
    const int chunk = gb / 18, sub = gb % 18;
    const int tp = sub >> 1;
    const int i = chunk * 256 + threadIdx.x;
    if (i >= NACT) return;
    const int pos = list[i];
    if (sub & 1) imp_part<14, 13>(i, pos, tp, h2, wimp, pbuf);
    else         imp_part<0, 14>(i, pos, tp, h2, wimp, pbuf);
}

// ---------------- imp combine: sum 9 parts -> kernel-mask bits + voxel logit ----------------
__global__ void __launch_bounds__(256) k_impc(const float* __restrict__ pbuf,
        uint32_t* __restrict__ u_logits, uint32_t* __restrict__ kbits) {
    const int i = blockIdx.x * 256 + threadIdx.x;
    if (i >= NACT) return;
    uint32_t bits = 0;
    float logit = 0.f;
    #pragma unroll
    for (int c = 0; c < 27; ++c) {
        float s = 0.f;
        #pragma unroll
        for (int tp = 0; tp < 9; ++tp)
            s += pbuf[(size_t)(tp * 27 + c) * NACT + i];
        if (c < 26) bits |= (s >= 0.f ? 1u : 0u) << c;
        else logit = s;
    }
    kbits[i] = bits;
    u_logits[i] = f2sort(logit);
}

// ---------------- exact kth-largest ----------------
__global__ void __launch_bounds__(256) k_select(const uint32_t* __restrict__ u_all,
                                                uint32_t* __restrict__ kth_u) {
    const int b = blockIdx.x;
    const uint32_t* u = u_all + (size_t)b * NVb;
    __shared__ int hist[256];
    __shared__ int s_d, s_above;
    uint32_t prefix = 0;
    int K = KFORE;
    for (int p = 3; p >= 0; --p) {
        hist[threadIdx.x] = 0;
        __syncthreads();
        const int sh = p * 8;
        for (int i = threadIdx.x; i < NVb; i += 256) {
            uint32_t ui = u[i];
            bool cand;
            if (p == 3) cand = true;
            else cand = ((ui >> (sh + 8)) == prefix);
            if (cand) atomicAdd(&hist[(ui >> sh) & 255], 1);
        }
        __syncthreads();
        if (threadIdx.x == 0) {
            int cum = 0, d = 255;
            for (; d >= 0; --d) { cum += hist[d]; if (cum >= K) break; }
            s_d = d; s_above = cum - hist[d];
        }
        __syncthreads();
        prefix = (prefix << 8) | (uint32_t)s_d;
        K -= s_above;
        __syncthreads();
    }
    if (threadIdx.x == 0) kth_u[b] = prefix;
}

// ---------------- dilation ----------------
__global__ void __launch_bounds__(256) k_dilate(const int* __restrict__ list,
                                                const uint32_t* __restrict__ u_logits,
                                                const uint32_t* __restrict__ kbits,
                                                const uint32_t* __restrict__ kth_u,
                                                uint8_t* __restrict__ new_act) {
    int i = blockIdx.x * 256 + threadIdx.x;
    if (i >= NACT) return;
    int pos = list[i];
    int b = pos >> 16;
    if (u_logits[i] < kth_u[b]) return;
    int z = (pos >> 12) & 15, y = (pos >> 6) & 63, x = pos & 63;
    uint32_t bits = kbits[i];
    while (bits) {
        int ch = __ffs(bits) - 1;
        bits &= bits - 1;
        int l = ch + (ch >= 13 ? 1 : 0);
        int oz = l / 9 - 1, oy = (l / 3) % 3 - 1, ox = l % 3 - 1;
        int tz = z + oz, ty = y + oy, tx = x + ox;
        if (tz >= 1 && tz < Dd && ty >= 1 && ty < Hh && tx >= 1 && tx < Ww)
            new_act[((b * Dd + tz) * Hh + ty) * Ww + tx] = 1;
    }
}

// ---------------- w_focal f32 [27][64][128] -> bf16 transposed [27][128][64] ----------------
__global__ void __launch_bounds__(256) k_wcvt(const float* __restrict__ wf,
                                              unsigned short* __restrict__ wfb) {
    int i = blockIdx.x * 256 + threadIdx.x;   // 221184 total
    int t = i >> 13, r = i & 8191, n = r >> 6, k = r & 63;
    wfb[i] = f2b(wf[(t * 64 + k) * 128 + n]);
}

// ---------------- focal conv 64->128 via bf16 MFMA, depth-2 gather pipeline ----------------
// 256 thr (4 waves), 64 voxels/block; wave wv owns 32 output ch (2 N-tiles).
// As XOR-swizzled (16B-slot ^ (row&7)) -> 0 bank conflicts (measured R8/R9).
// Pipeline: at macro-iter (taps t,t+1): rA holds gather(t+2), rB holds gather(t+3).
__global__ void __launch_bounds__(256, 4) k_focal(
        const int* __restrict__ list, const int* __restrict__ count,
        const unsigned short* __restrict__ h2b, const unsigned short* __restrict__ wfb,
        const float* __restrict__ g, const float* __restrict__ bta,
        const float* __restrict__ mu, const float* __restrict__ va,
        float* __restrict__ out, const unsigned short* __restrict__ zb) {
    __shared__ __align__(16) unsigned short As[2][64 * 64];  // swizzled, no pad
    __shared__ int s_pos[64];
    const int n = *count;
    const int i0 = xcd_swz(blockIdx.x, 2048) * 64;
    if (i0 >= n) return;
    const int tid = threadIdx.x;
    const int wv = tid >> 6, lane = tid & 63;
    if (tid < 64) { int idx = i0 + tid; s_pos[tid] = idx < n ? list[idx] : -1; }
    __syncthreads();
    const int v0 = tid >> 3, c8 = tid & 7, v1 = v0 + 32;   // each thread stages rows v0, v1
    const int p0 = s_pos[v0], p1 = s_pos[v1];
    const int z0 = (p0 >> 12) & 15, y0 = (p0 >> 6) & 63, x0 = p0 & 63;
    const int z1 = (p1 >> 12) & 15, y1 = (p1 >> 6) & 63, x1 = p1 & 63;
    const int wslot = (c8 ^ (v0 & 7)) << 3;                 // v1&7 == v0&7
    const int wa0 = v0 * 64 + wslot, wa1 = v1 * 64 + wslot;
    const int hi = lane >> 4, lo = lane & 15;
    const int cb = wv * 32;

    f32x4 acc[4][2];
    #pragma unroll
    for (int mi = 0; mi < 4; ++mi)
        #pragma unroll
        for (int ni = 0; ni < 2; ++ni) acc[mi][ni] = (f32x4){0.f, 0.f, 0.f, 0.f};

    auto gather = [&](int t, short8& r0, short8& r1) {
        int dz = t / 9 - 1, dy = (t / 3) % 3 - 1, dx = t % 3 - 1;
        int off = dz * 4096 + dy * 64 + dx;
        bool ok0 = p0 >= 0 && (unsigned)(z0 + dz) < Dd && (unsigned)(y0 + dy) < Hh && (unsigned)(x0 + dx) < Ww;
        bool ok1 = p1 >= 0 && (unsigned)(z1 + dz) < Dd && (unsigned)(y1 + dy) < Hh && (unsigned)(x1 + dx) < Ww;
        r0 = *(const short8*)(ok0 ? h2b + (size_t)(p0 + off) * 64 + c8 * 8 : zb);
        r1 = *(const short8*)(ok1 ? h2b + (size_t)(p1 + off) * 64 + c8 * 8 : zb);
    };

    auto compute = [&](int t, int buf) {
        short8 bfr[2][2];
        #pragma unroll
        for (int ni = 0; ni < 2; ++ni)
            #pragma unroll
            for (int ks = 0; ks < 2; ++ks)
                bfr[ni][ks] = *(const short8*)(wfb + (size_t)t * 8192
                                + (size_t)(cb + ni * 16 + lo) * 64 + ks * 32 + hi * 8);
        #pragma unroll
        for (int ks = 0; ks < 2; ++ks) {
            const int rs = ((ks * 4 + hi) ^ (lo & 7)) << 3;
            short8 a[4];
            #pragma unroll
            for (int mi = 0; mi < 4; ++mi)
                a[mi] = *(const short8*)&As[buf][(mi * 16 + lo) * 64 + rs];
            #pragma unroll
            for (int mi = 0; mi < 4; ++mi)
                #pragma unroll
                for (int ni = 0; ni < 2; ++ni)
                    acc[mi][ni] = __builtin_amdgcn_mfma_f32_16x16x32_bf16(
                        a[mi], bfr[ni][ks], acc[mi][ni], 0, 0, 0);
        }
    };

    short8 rA0, rA1, rB0, rB1;
    // prologue: taps 0,1 -> LDS; taps 2,3 in flight in rA,rB
    gather(0, rA0, rA1);
    gather(1, rB0, rB1);
    *(short8*)&As[0][wa0] = rA0; *(short8*)&As[0][wa1] = rA1;
    *(short8*)&As[1][wa0] = rB0; *(short8*)&As[1][wa1] = rB1;
    gather(2, rA0, rA1);
    gather(3, rB0, rB1);
    __syncthreads();

    for (int t = 0; t < 26; t += 2) {
        compute(t, 0);
        __syncthreads();                       // all waves done reading As[0]
        if (t + 2 <= 26) {
            *(short8*)&As[0][wa0] = rA0;       // tap t+2 (waits its own vmcnt only)
            *(short8*)&As[0][wa1] = rA1;
            if (t + 4 <= 26) gather(t + 4, rA0, rA1);
        }
        compute(t + 1, 1);
        __syncthreads();                       // done reading As[1]; As[0] write visible
        if (t + 3 <= 26) {
            *(short8*)&As[1][wa0] = rB0;       // tap t+3
            *(short8*)&As[1][wa1] = rB1;
            if (t + 5 <= 26) gather(t + 5, rB0, rB1);
        }
        if (t + 2 > 26) break;
    }
    __syncthreads();                           // As[0]=tap 26 write visible
    compute(26, 0);

    #pragma unroll
    for (int ni = 0; ni < 2; ++ni) {
        const int ch = cb + ni * 16 + lo;
        const float s = g[ch] * (1.0f / sqrtf(va[ch] + EPSf));
        const float sh = bta[ch], mm = mu[ch];
        #pragma unroll
        for (int mi = 0; mi < 4; ++mi)
            #pragma unroll
            for (int j = 0; j < 4; ++j) {
                int vi = mi * 16 + hi * 4 + j;
                if (i0 + vi < n)
                    out[(size_t)s_pos[vi] * 128 + ch] = fmaxf(0.f, fmaf(acc[mi][ni][j] - mm, s, sh));
            }
    }
}

extern "C" void kernel_launch(void* const* d_in, const int* in_sizes, int n_in,
                              void* d_out, int out_size, void* d_ws, size_t ws_size,
                              hipStream_t stream) {
    (void)in_sizes; (void)n_in; (void)ws_size;
    const float* feat   = (const float*)d_in[0];
    const int*   coords = (const int*)d_in[1];
    const float* w1   = (const float*)d_in[2];
    const float* w2   = (const float*)d_in[3];
    const float* wimp = (const float*)d_in[4];
    const float* wf   = (const float*)d_in[5];
    const float* g1 = (const float*)d_in[6],  *b1 = (const float*)d_in[7];
    const float* m1 = (const float*)d_in[8],  *v1 = (const float*)d_in[9];
    const float* g2 = (const float*)d_in[10], *b2 = (const float*)d_in[11];
    const float* m2 = (const float*)d_in[12], *v2 = (const float*)d_in[13];
    const float* g3 = (const float*)d_in[14], *b3 = (const float*)d_in[15];
    const float* m3 = (const float*)d_in[16], *v3 = (const float*)d_in[17];

    char* ws = (char*)d_ws;
    float*    dense16  = (float*)(ws + 0);           //  8,388,608 B (wfb overlays after conv1p)
    float*    h1       = (float*)(ws + 8388608);     // 16,777,216 B (h2b overlays after conv2p)
    float*    h2       = (float*)(ws + 25165824);    // 33,554,432 B
    uint8_t*  active   = (uint8_t*)(ws + 58720256);  //    131,072 B
    uint8_t*  new_act  = (uint8_t*)(ws + 58851328);  //    131,072 B
    float*    zrow     = (float*)(ws + 58982400);    //        256 B zeros
    int*      count    = (int*)(ws + 58982656);      //        256 B
    const size_t MEMSET_BYTES = 58982912;
    uint32_t* u_logits = (uint32_t*)(ws + 58982912); //    160,000 B
    uint32_t* kbits    = (uint32_t*)(ws + 59142912); //    160,000 B (also bcnt/boff scratch)
    uint32_t* kth_u    = (uint32_t*)(ws + 59302912); //        256 B
    int*      list     = (int*)(ws + 59303168);      //    524,288 B (act list, then focal list)

    unsigned short* wfb = (unsigned short*)dense16;  // [27][128][64] bf16, after conv1p
    unsigned short* h2b = (unsigned short*)h1;       // [131072][64] bf16, after conv2p+memset
    float* pbuf = (float*)d_out;                     // partial-sum scratch (used BEFORE d_out memset)
    int* bcnt = (int*)kbits;                         // 512 ints (dead region at both compact times)
    int* boff = (int*)kbits + 512;                   // 512 ints

    hipMemsetAsync(d_ws, 0, MEMSET_BYTES, stream);

    k_scatter<<<157, 256, 0, stream>>>(feat, coords, dense16, active, new_act);
    k_cnt<<<512, 256, 0, stream>>>(active, bcnt);                       // ordered active list
    k_scan<<<1, 512, 0, stream>>>(bcnt, boff, count);
    k_emit<<<512, 256, 0, stream>>>(active, boff, list);
    k_conv1p<<<157 * 12, 256, 0, stream>>>(list, dense16, w1, pbuf);
    k_conv1c<<<157, 256, 0, stream>>>(list, pbuf, g1, b1, m1, v1, h1);
    k_wcvt<<<864, 256, 0, stream>>>(wf, wfb);                           // dense16 now dead
    k_conv2p<<<157 * 12, 256, 0, stream>>>(list, h1, w2, pbuf);
    hipMemsetAsync(h2b, 0, (size_t)131072 * 64 * 2, stream);            // h1 dead; zero inactive h2b rows
    k_conv2c<<<157, 256, 0, stream>>>(list, pbuf, g2, b2, m2, v2, h2, h2b);
    k_impp<<<157 * 18, 256, 0, stream>>>(list, h2, wimp, pbuf);
    k_impc<<<157, 256, 0, stream>>>(pbuf, u_logits, kbits);
    hipMemsetAsync(d_out, 0, (size_t)out_size * sizeof(float), stream); // scratch done; zero output
    k_select<<<2, 256, 0, stream>>>(u_logits, kth_u);
    k_dilate<<<157, 256, 0, stream>>>(list, u_logits, kbits, kth_u, new_act);
    k_cnt<<<512, 256, 0, stream>>>(new_act, bcnt);                      // focal list (kbits dead now)
    k_scan<<<1, 512, 0, stream>>>(bcnt, boff, count);
    k_emit<<<512, 256, 0, stream>>>(new_act, boff, list);
    k_focal<<<2048, 256, 0, stream>>>(list, count, h2b, wfb, g3, b3, m3, v3,
                                      (float*)d_out, (const unsigned short*)zrow);
}

// Round 14
// 529.229 us; speedup vs baseline: 1.8243x; 1.0249x over previous
//
#include <hip/hip_runtime.h>
#include <stdint.h>

#define Dd 16
#define Hh 64
#define Ww 64
#define NACT 40000
#define NVb 20000
#define KFORE 10000
#define EPSf 0.001f

typedef __attribute__((ext_vector_type(8))) short short8;   // 8 bf16 (4 VGPR)
typedef __attribute__((ext_vector_type(4))) float f32x4;
typedef __attribute__((ext_vector_type(4))) unsigned short us4;

static __device__ __forceinline__ uint32_t f2sort(float f) {
    uint32_t u = __float_as_uint(f);
    return (u & 0x80000000u) ? ~u : (u | 0x80000000u);
}

// round-to-nearest-even f32 -> bf16 bits (inputs finite)
static __device__ __forceinline__ unsigned short f2b(float f) {
    uint32_t u = __float_as_uint(f);
    return (unsigned short)((u + 0x7FFFu + ((u >> 16) & 1u)) >> 16);
}

// bijective XCD-contiguous remap (m204)
static __device__ __forceinline__ int xcd_swz(int orig, int nwg) {
    int xcd = orig & 7, idx = orig >> 3;
    int q = nwg >> 3, r = nwg & 7;
    int base = xcd < r ? xcd * (q + 1) : r * (q + 1) + (xcd - r) * q;
    return base + idx;
}

// ---------------- scatter features to dense grid ----------------
__global__ void __launch_bounds__(256) k_scatter(const float* __restrict__ feat,
                                                 const int* __restrict__ coords,
                                                 float* __restrict__ dense16,
                                                 uint8_t* __restrict__ active,
                                                 uint8_t* __restrict__ new_act) {
    int i = blockIdx.x * 256 + threadIdx.x;
    if (i >= NACT) return;
    int b = coords[i * 4 + 0], z = coords[i * 4 + 1], y = coords[i * 4 + 2], x = coords[i * 4 + 3];
    int pos = ((b * Dd + z) * Hh + y) * Ww + x;
    active[pos] = 1;
    new_act[pos] = 1;
    const float4* f4 = (const float4*)(feat + (size_t)i * 16);
    float4* d4 = (float4*)(dense16 + (size_t)pos * 16);
    d4[0] = f4[0]; d4[1] = f4[1]; d4[2] = f4[2]; d4[3] = f4[3];
}

// ---------------- parallel ordered compaction: count -> scan -> emit ----------------
__global__ void __launch_bounds__(256) k_cnt(const uint8_t* __restrict__ mask,
                                             int* __restrict__ bcnt) {
    __shared__ int s[256];
    const int i = blockIdx.x * 256 + threadIdx.x;
    s[threadIdx.x] = mask[i] ? 1 : 0;
    __syncthreads();
    for (int off = 128; off > 0; off >>= 1) {
        if (threadIdx.x < off) s[threadIdx.x] += s[threadIdx.x + off];
        __syncthreads();
    }
    if (threadIdx.x == 0) bcnt[blockIdx.x] = s[0];
}

__global__ void __launch_bounds__(512) k_scan(const int* __restrict__ bcnt,
                                              int* __restrict__ boff, int* __restrict__ count) {
    __shared__ int s[512];
    const int t = threadIdx.x;
    const int v0 = bcnt[t];
    s[t] = v0;
    __syncthreads();
    for (int off = 1; off < 512; off <<= 1) {
        int v = s[t];
        if (t >= off) v += s[t - off];
        __syncthreads();
        s[t] = v;
        __syncthreads();
    }
    boff[t] = s[t] - v0;           // exclusive prefix
    if (t == 511) *count = s[511];
}

__global__ void __launch_bounds__(256) k_emit(const uint8_t* __restrict__ mask,
                                              const int* __restrict__ boff,
                                              int* __restrict__ list) {
    __shared__ int s[256];
    const int i = blockIdx.x * 256 + threadIdx.x;
    const int pred = mask[i] ? 1 : 0;
    s[threadIdx.x] = pred;
    __syncthreads();
    for (int off = 1; off < 256; off <<= 1) {
        int v = s[threadIdx.x];
        if (threadIdx.x >= off) v += s[threadIdx.x - off];
        __syncthreads();
        s[threadIdx.x] = v;
        __syncthreads();
    }
    if (pred) list[boff[blockIdx.x] + s[threadIdx.x] - 1] = i;
}

// ---------------- conv1 parts: 3 tap-parts x 4 ch-groups (8 ch) -> partial[tp][c][i] ----------------
__global__ void __launch_bounds__(256) k_conv1p(const int* __restrict__ list,
        const float* __restrict__ dense16, const float* __restrict__ w1,
        float* __restrict__ pbuf) {
    const int gb = xcd_swz(blockIdx.x, 157 * 12);
    const int chunk = gb / 12, sub = gb % 12;
    const int tp = sub >> 2, cb = (sub & 3) * 8;
    const int i = chunk * 256 + threadIdx.x;
    if (i >= NACT) return;
    const int pos = list[i];
    const int z = (pos >> 12) & 15, y = (pos >> 6) & 63, x = pos & 63;
    float acc[8];
    #pragma unroll
    for (int c = 0; c < 8; ++c) acc[c] = 0.f;
    const int dz = tp - 1;
    if ((unsigned)(z + dz) < Dd) {
        for (int tt = 0; tt < 9; ++tt) {
            const int dy = tt / 3 - 1, dx = tt % 3 - 1;
            if (!((unsigned)(y + dy) < Hh && (unsigned)(x + dx) < Ww)) continue;
            const float* row = dense16 + (size_t)(pos + dz * 4096 + dy * 64 + dx) * 16;
            const float* wt = w1 + (tp * 9 + tt) * 512 + cb;
            #pragma unroll
            for (int k4 = 0; k4 < 4; ++k4) {
                float4 xv = *(const float4*)(row + k4 * 4);
                float xs[4] = {xv.x, xv.y, xv.z, xv.w};
                #pragma unroll
                for (int j = 0; j < 4; ++j)
                    #pragma unroll
                    for (int c = 0; c < 8; ++c)
                        acc[c] = fmaf(xs[j], wt[(k4 * 4 + j) * 32 + c], acc[c]);
            }
        }
    }
    #pragma unroll
    for (int c = 0; c < 8; ++c) pbuf[(size_t)(tp * 32 + cb + c) * NACT + i] = acc[c];
}

// ---------------- conv1 combine: sum 3 parts + BN + ReLU -> h1 ----------------
__global__ void __launch_bounds__(256) k_conv1c(const int* __restrict__ list,
        const float* __restrict__ pbuf,
        const float* __restrict__ g, const float* __restrict__ bta,
        const float* __restrict__ mu, const float* __restrict__ va,
        float* __restrict__ h1) {
    const int i = blockIdx.x * 256 + threadIdx.x;
    if (i >= NACT) return;
    const int pos = list[i];
    float res[32];
    #pragma unroll
    for (int c = 0; c < 32; ++c) {
        float s = pbuf[(size_t)c * NACT + i]
                + pbuf[(size_t)(32 + c) * NACT + i]
                + pbuf[(size_t)(64 + c) * NACT + i];
        const float sc = g[c] * (1.0f / sqrtf(va[c] + EPSf));
        res[c] = fmaxf(0.f, fmaf(s - mu[c], sc, bta[c]));
    }
    #pragma unroll
    for (int c4 = 0; c4 < 8; ++c4)
        *(float4*)(h1 + (size_t)pos * 32 + c4 * 4) = *(float4*)&res[c4 * 4];
}

// ---------------- conv2 parts: 3 tap-parts x 4 ch-groups (16 ch) -> partial[tp][c][i] ----------------
__global__ void __launch_bounds__(256) k_conv2p(const int* __restrict__ list,
        const float* __restrict__ h1, const float* __restrict__ w2,
        float* __restrict__ pbuf) {
    const int gb = xcd_swz(blockIdx.x, 157 * 12);
    const int chunk = gb / 12, sub = gb % 12;
    const int tp = sub >> 2, cb = (sub & 3) * 16;
    const int i = chunk * 256 + threadIdx.x;
    if (i >= NACT) return;
    const int pos = list[i];
    const int z = (pos >> 12) & 15, y = (pos >> 6) & 63, x = pos & 63;
    float acc[16];
    #pragma unroll
    for (int c = 0; c < 16; ++c) acc[c] = 0.f;
    const int dz = tp - 1;
    if ((unsigned)(z + dz) < Dd) {
        for (int tt = 0; tt < 9; ++tt) {
            const int dy = tt / 3 - 1, dx = tt % 3 - 1;
            if (!((unsigned)(y + dy) < Hh && (unsigned)(x + dx) < Ww)) continue;
            const float* row = h1 + (size_t)(pos + dz * 4096 + dy * 64 + dx) * 32;
            const float* wt = w2 + (tp * 9 + tt) * 2048 + cb;
            #pragma unroll
            for (int k4 = 0; k4 < 8; ++k4) {
                float4 xv = *(const float4*)(row + k4 * 4);
                float xs[4] = {xv.x, xv.y, xv.z, xv.w};
                #pragma unroll
                for (int j = 0; j < 4; ++j)
                    #pragma unroll
                    for (int c = 0; c < 16; ++c)
                        acc[c] = fmaf(xs[j], wt[(k4 * 4 + j) * 64 + c], acc[c]);
            }
        }
    }
    #pragma unroll
    for (int c = 0; c < 16; ++c) pbuf[(size_t)(tp * 64 + cb + c) * NACT + i] = acc[c];
}

// ---------------- conv2 combine: sum 3 tap-parts + BN + ReLU -> h2 (f32) + h2b (bf16) ----------------
__global__ void __launch_bounds__(256) k_conv2c(const int* __restrict__ list,
        const float* __restrict__ pbuf,
        const float* __restrict__ g, const float* __restrict__ bta,
        const float* __restrict__ mu, const float* __restrict__ va,
        float* __restrict__ h2, unsigned short* __restrict__ h2b) {
    const int i = blockIdx.x * 256 + threadIdx.x;
    if (i >= NACT) return;
    const int pos = list[i];
    float res[64];
    #pragma unroll
    for (int c = 0; c < 64; ++c) {
        float s = pbuf[(size_t)c * NACT + i]
                + pbuf[(size_t)(64 + c) * NACT + i]
                + pbuf[(size_t)(128 + c) * NACT + i];
        const float sc = g[c] * (1.0f / sqrtf(va[c] + EPSf));
        res[c] = fmaxf(0.f, fmaf(s - mu[c], sc, bta[c]));
    }
    #pragma unroll
    for (int c4 = 0; c4 < 16; ++c4)
        *(float4*)(h2 + (size_t)pos * 64 + c4 * 4) = *(float4*)&res[c4 * 4];
    #pragma unroll
    for (int c4 = 0; c4 < 16; ++c4) {
        us4 o = { f2b(res[c4 * 4]), f2b(res[c4 * 4 + 1]), f2b(res[c4 * 4 + 2]), f2b(res[c4 * 4 + 3]) };
        *(us4*)(h2b + (size_t)pos * 64 + c4 * 4) = o;
    }
}

// ---------------- imp parts: 9 tap-parts x 2 ch-halves -> partial[tp][c][i] ----------------
template<int CB, int NC>
static __device__ __forceinline__ void imp_part(int i, int pos, int tp,
        const float* __restrict__ h2, const float* __restrict__ wimp,
        float* __restrict__ pbuf) {
    const int z = (pos >> 12) & 15, y = (pos >> 6) & 63, x = pos & 63;
    float acc[NC];
    #pragma unroll
    for (int c = 0; c < NC; ++c) acc[c] = 0.f;
    for (int tt = 0; tt < 3; ++tt) {
        const int t = tp * 3 + tt;
        const int dz = t / 9 - 1, dy = (t / 3) % 3 - 1, dx = t % 3 - 1;
        if (!((unsigned)(z + dz) < Dd && (unsigned)(y + dy) < Hh && (unsigned)(x + dx) < Ww)) continue;
        const float* row = h2 + (size_t)(pos + dz * 4096 + dy * 64 + dx) * 64;
        const float* wt = wimp + t * 1728 + CB;
        #pragma unroll
        for (int k4 = 0; k4 < 16; ++k4) {
            float4 xv = *(const float4*)(row + k4 * 4);
            float xs[4] = {xv.x, xv.y, xv.z, xv.w};
            #pragma unroll
            for (int j = 0; j < 4; ++j)
                #pragma unroll
                for (int c = 0; c < NC; ++c)
                    acc[c] = fmaf(xs[j], wt[(k4 * 4 + j) * 27 + c], acc[c]);
        }
    }
    #pragma unroll
    for (int c = 0; c < NC; ++c) pbuf[(size_t)(tp * 27 + CB + c) * NACT + i] = acc[c];
}

__global__ void __launch_bounds__(256) k_impp(const int* __restrict__ list,
        const float* __restrict__ h2, const float* __restrict__ wimp,
        float* __restrict__ pbuf) {
    const int gb = xcd_swz(blockIdx.x, 157 * 18);
    const int chunk = gb / 18, sub = gb % 18;
    const int tp = sub >> 1;
    const int i = chunk * 256 + threadIdx.x;
    if (i >= NACT) return;
    const int pos = list[i];
    if (sub & 1) imp_part<14, 13>(i, pos, tp, h2, wimp, pbuf);
    else         imp_part<0, 14>(i, pos, tp, h2, wimp, pbuf);
}

// ---------------- imp combine: sum 9 parts -> kernel-mask bits + voxel logit ----------------
__global__ void __launch_bounds__(256) k_impc(const float* __restrict__ pbuf,
        uint32_t* __restrict__ u_logits, uint32_t* __restrict__ kbits) {
    const int i = blockIdx.x * 256 + threadIdx.x;
    if (i >= NACT) return;
    uint32_t bits = 0;
    float logit = 0.f;
    #pragma unroll
    for (int c = 0; c < 27; ++c) {
        float s = 0.f;
        #pragma unroll
        for (int tp = 0; tp < 9; ++tp)
            s += pbuf[(size_t)(tp * 27 + c) * NACT + i];
        if (c < 26) bits |= (s >= 0.f ? 1u : 0u) << c;
        else logit = s;
    }
    kbits[i] = bits;
    u_logits[i] = f2sort(logit);
}

// ---------------- exact kth-largest ----------------
__global__ void __launch_bounds__(256) k_select(const uint32_t* __restrict__ u_all,
                                                uint32_t* __restrict__ kth_u) {
    const int b = blockIdx.x;
    const uint32_t* u = u_all + (size_t)b * NVb;
    __shared__ int hist[256];
    __shared__ int s_d, s_above;
    uint32_t prefix = 0;
    int K = KFORE;
    for (int p = 3; p >= 0; --p) {
        hist[threadIdx.x] = 0;
        __syncthreads();
        const int sh = p * 8;
        for (int i = threadIdx.x; i < NVb; i += 256) {
            uint32_t ui = u[i];
            bool cand;
            if (p == 3) cand = true;
            else cand = ((ui >> (sh + 8)) == prefix);
            if (cand) atomicAdd(&hist[(ui >> sh) & 255], 1);
        }
        __syncthreads();
        if (threadIdx.x == 0) {
            int cum = 0, d = 255;
            for (; d >= 0; --d) { cum += hist[d]; if (cum >= K) break; }
            s_d = d; s_above = cum - hist[d];
        }
        __syncthreads();
        prefix = (prefix << 8) | (uint32_t)s_d;
        K -= s_above;
        __syncthreads();
    }
    if (threadIdx.x == 0) kth_u[b] = prefix;
}

// ---------------- dilation ----------------
__global__ void __launch_bounds__(256) k_dilate(const int* __restrict__ list,
                                                const uint32_t* __restrict__ u_logits,
                                                const uint32_t* __restrict__ kbits,
                                                const uint32_t* __restrict__ kth_u,
                                                uint8_t* __restrict__ new_act) {
    int i = blockIdx.x * 256 + threadIdx.x;
    if (i >= NACT) return;
    int pos = list[i];
    int b = pos >> 16;
    if (u_logits[i] < kth_u[b]) return;
    int z = (pos >> 12) & 15, y = (pos >> 6) & 63, x = pos & 63;
    uint32_t bits = kbits[i];
    while (bits) {
        int ch = __ffs(bits) - 1;
        bits &= bits - 1;
        int l = ch + (ch >= 13 ? 1 : 0);
        int oz = l / 9 - 1, oy = (l / 3) % 3 - 1, ox = l % 3 - 1;
        int tz = z + oz, ty = y + oy, tx = x + ox;
        if (tz >= 1 && tz < Dd && ty >= 1 && ty < Hh && tx >= 1 && tx < Ww)
            new_act[((b * Dd + tz) * Hh + ty) * Ww + tx] = 1;
    }
}

// ---------------- zero output rows NOT in new_act (replaces 67MB memset) ----------------
__global__ void __launch_bounds__(256) k_zero(const uint8_t* __restrict__ new_act,
                                              float* __restrict__ out) {
    const int pos = blockIdx.x * 256 + threadIdx.x;   // 512 blocks x 256 = 131072
    if (new_act[pos]) return;                          // will be fully written by k_focal
    float4 z = {0.f, 0.f, 0.f, 0.f};
    float4* o = (float4*)(out + (size_t)pos * 128);
    #pragma unroll
    for (int j = 0; j < 32; ++j) o[j] = z;
}

// ---------------- w_focal f32 [27][64][128] -> bf16 transposed [27][128][64] ----------------
__global__ void __launch_bounds__(256) k_wcvt(const float* __restrict__ wf,
                                              unsigned short* __restrict__ wfb) {
    int i = blockIdx.x * 256 + threadIdx.x;   // 221184 total
    int t = i >> 13, r = i & 8191, n = r >> 6, k = r & 63;
    wfb[i] = f2b(wf[(t * 64 + k) * 128 + n]);
}

// ---------------- focal conv 64->128 via bf16 MFMA, depth-2 gather + weight prefetch ----------------
// 256 thr (4 waves), 64 voxels/block; wave wv owns 32 output ch (2 N-tiles).
// As XOR-swizzled (16B-slot ^ (row&7)) -> 0 bank conflicts (measured R8/R9/R13).
// A-gathers: depth-2 (rA=t+2, rB=t+3). Weights: register-prefetched 1.5 taps ahead (wE/wO).
__global__ void __launch_bounds__(256, 4) k_focal(
        const int* __restrict__ list, const int* __restrict__ count,
        const unsigned short* __restrict__ h2b, const unsigned short* __restrict__ wfb,
        const float* __restrict__ g, const float* __restrict__ bta,
        const float* __restrict__ mu, const float* __restrict__ va,
        float* __restrict__ out, const unsigned short* __restrict__ zb) {
    __shared__ __align__(16) unsigned short As[2][64 * 64];  // swizzled, no pad
    __shared__ int s_pos[64];
    const int n = *count;
    const int i0 = xcd_swz(blockIdx.x, 2048) * 64;
    if (i0 >= n) return;
    const int tid = threadIdx.x;
    const int wv = tid >> 6, lane = tid & 63;
    if (tid < 64) { int idx = i0 + tid; s_pos[tid] = idx < n ? list[idx] : -1; }
    __syncthreads();
    const int v0 = tid >> 3, c8 = tid & 7, v1 = v0 + 32;   // each thread stages rows v0, v1
    const int p0 = s_pos[v0], p1 = s_pos[v1];
    const int z0 = (p0 >> 12) & 15, y0 = (p0 >> 6) & 63, x0 = p0 & 63;
    const int z1 = (p1 >> 12) & 15, y1 = (p1 >> 6) & 63, x1 = p1 & 63;
    const int wslot = (c8 ^ (v0 & 7)) << 3;                 // v1&7 == v0&7
    const int wa0 = v0 * 64 + wslot, wa1 = v1 * 64 + wslot;
    const int hi = lane >> 4, lo = lane & 15;
    const int cb = wv * 32;

    f32x4 acc[4][2];
    #pragma unroll
    for (int mi = 0; mi < 4; ++mi)
        #pragma unroll
        for (int ni = 0; ni < 2; ++ni) acc[mi][ni] = (f32x4){0.f, 0.f, 0.f, 0.f};

    auto gather = [&](int t, short8& r0, short8& r1) {
        int dz = t / 9 - 1, dy = (t / 3) % 3 - 1, dx = t % 3 - 1;
        int off = dz * 4096 + dy * 64 + dx;
        bool ok0 = p0 >= 0 && (unsigned)(z0 + dz) < Dd && (unsigned)(y0 + dy) < Hh && (unsigned)(x0 + dx) < Ww;
        bool ok1 = p1 >= 0 && (unsigned)(z1 + dz) < Dd && (unsigned)(y1 + dy) < Hh && (unsigned)(x1 + dx) < Ww;
        r0 = *(const short8*)(ok0 ? h2b + (size_t)(p0 + off) * 64 + c8 * 8 : zb);
        r1 = *(const short8*)(ok1 ? h2b + (size_t)(p1 + off) * 64 + c8 * 8 : zb);
    };

    auto load_w = [&](int t, short8 (&w)[2][2]) {
        #pragma unroll
        for (int ni = 0; ni < 2; ++ni)
            #pragma unroll
            for (int ks = 0; ks < 2; ++ks)
                w[ni][ks] = *(const short8*)(wfb + (size_t)t * 8192
                                + (size_t)(cb + ni * 16 + lo) * 64 + ks * 32 + hi * 8);
    };

    auto compute = [&](int buf, const short8 (&w)[2][2]) {
        #pragma unroll
        for (int ks = 0; ks < 2; ++ks) {
            const int rs = ((ks * 4 + hi) ^ (lo & 7)) << 3;
            short8 a[4];
            #pragma unroll
            for (int mi = 0; mi < 4; ++mi)
                a[mi] = *(const short8*)&As[buf][(mi * 16 + lo) * 64 + rs];
            #pragma unroll
            for (int mi = 0; mi < 4; ++mi)
                #pragma unroll
                for (int ni = 0; ni < 2; ++ni)
                    acc[mi][ni] = __builtin_amdgcn_mfma_f32_16x16x32_bf16(
                        a[mi], w[ni][ks], acc[mi][ni], 0, 0, 0);
        }
    };

    short8 rA0, rA1, rB0, rB1;
    short8 wE[2][2], wO[2][2];
    // prologue: taps 0,1 -> LDS; taps 2,3 gathers in flight; weights 0,1 in regs
    gather(0, rA0, rA1);
    gather(1, rB0, rB1);
    *(short8*)&As[0][wa0] = rA0; *(short8*)&As[0][wa1] = rA1;
    *(short8*)&As[1][wa0] = rB0; *(short8*)&As[1][wa1] = rB1;
    gather(2, rA0, rA1);
    gather(3, rB0, rB1);
    load_w(0, wE);
    load_w(1, wO);
    __syncthreads();

    for (int t = 0; t < 26; t += 2) {
        compute(0, wE);                        // tap t (MFMA reads wE, then refill below)
        if (t + 2 <= 26) load_w(t + 2, wE);    // ~1.5 taps of lead
        __syncthreads();                       // all waves done reading As[0]
        if (t + 2 <= 26) {
            *(short8*)&As[0][wa0] = rA0;       // tap t+2 (waits its own vmcnt only)
            *(short8*)&As[0][wa1] = rA1;
            if (t + 4 <= 26) gather(t + 4, rA0, rA1);
        }
        compute(1, wO);                        // tap t+1
        if (t + 3 <= 26) load_w(t + 3, wO);
        __syncthreads();                       // done reading As[1]; As[0] write visible
        if (t + 3 <= 26) {
            *(short8*)&As[1][wa0] = rB0;       // tap t+3
            *(short8*)&As[1][wa1] = rB1;
            if (t + 5 <= 26) gather(t + 5, rB0, rB1);
        }
        if (t + 2 > 26) break;
    }
    __syncthreads();                           // As[0]=tap 26 write visible
    compute(0, wE);                            // tap 26

    #pragma unroll
    for (int ni = 0; ni < 2; ++ni) {
        const int ch = cb + ni * 16 + lo;
        const float s = g[ch] * (1.0f / sqrtf(va[ch] + EPSf));
        const float sh = bta[ch], mm = mu[ch];
        #pragma unroll
        for (int mi = 0; mi < 4; ++mi)
            #pragma unroll
            for (int j = 0; j < 4; ++j) {
                int vi = mi * 16 + hi * 4 + j;
                if (i0 + vi < n)
                    out[(size_t)s_pos[vi] * 128 + ch] = fmaxf(0.f, fmaf(acc[mi][ni][j] - mm, s, sh));
            }
    }
}

extern "C" void kernel_launch(void* const* d_in, const int* in_sizes, int n_in,
                              void* d_out, int out_size, void* d_ws, size_t ws_size,
                              hipStream_t stream) {
    (void)in_sizes; (void)n_in; (void)ws_size; (void)out_size;
    const float* feat   = (const float*)d_in[0];
    const int*   coords = (const int*)d_in[1];
    const float* w1   = (const float*)d_in[2];
    const float* w2   = (const float*)d_in[3];
    const float* wimp = (const float*)d_in[4];
    const float* wf   = (const float*)d_in[5];
    const float* g1 = (const float*)d_in[6],  *b1 = (const float*)d_in[7];
    const float* m1 = (const float*)d_in[8],  *v1 = (const float*)d_in[9];
    const float* g2 = (const float*)d_in[10], *b2 = (const float*)d_in[11];
    const float* m2 = (const float*)d_in[12], *v2 = (const float*)d_in[13];
    const float* g3 = (const float*)d_in[14], *b3 = (const float*)d_in[15];
    const float* m3 = (const float*)d_in[16], *v3 = (const float*)d_in[17];

    char* ws = (char*)d_ws;
    float*    dense16  = (float*)(ws + 0);           //  8,388,608 B (wfb overlays after conv1p)
    float*    h1       = (float*)(ws + 8388608);     // 16,777,216 B (h2b overlays after conv2p)
    float*    h2       = (float*)(ws + 25165824);    // 33,554,432 B
    uint8_t*  active   = (uint8_t*)(ws + 58720256);  //    131,072 B
    uint8_t*  new_act  = (uint8_t*)(ws + 58851328);  //    131,072 B
    float*    zrow     = (float*)(ws + 58982400);    //        256 B zeros
    int*      count    = (int*)(ws + 58982656);      //        256 B
    const size_t MEMSET_BYTES = 58982912;
    uint32_t* u_logits = (uint32_t*)(ws + 58982912); //    160,000 B
    uint32_t* kbits    = (uint32_t*)(ws + 59142912); //    160,000 B (also bcnt/boff scratch)
    uint32_t* kth_u    = (uint32_t*)(ws + 59302912); //        256 B
    int*      list     = (int*)(ws + 59303168);      //    524,288 B (act list, then focal list)

    unsigned short* wfb = (unsigned short*)dense16;  // [27][128][64] bf16, after conv1p
    unsigned short* h2b = (unsigned short*)h1;       // [131072][64] bf16, after conv2p+memset
    float* pbuf = (float*)d_out;                     // partial-sum scratch (used BEFORE out is written)
    int* bcnt = (int*)kbits;                         // 512 ints (dead region at both compact times)
    int* boff = (int*)kbits + 512;                   // 512 ints

    hipMemsetAsync(d_ws, 0, MEMSET_BYTES, stream);

    k_scatter<<<157, 256, 0, stream>>>(feat, coords, dense16, active, new_act);
    k_cnt<<<512, 256, 0, stream>>>(active, bcnt);                       // ordered active list
    k_scan<<<1, 512, 0, stream>>>(bcnt, boff, count);
    k_emit<<<512, 256, 0, stream>>>(active, boff, list);
    k_conv1p<<<157 * 12, 256, 0, stream>>>(list, dense16, w1, pbuf);
    k_conv1c<<<157, 256, 0, stream>>>(list, pbuf, g1, b1, m1, v1, h1);
    k_wcvt<<<864, 256, 0, stream>>>(wf, wfb);                           // dense16 now dead
    k_conv2p<<<157 * 12, 256, 0, stream>>>(list, h1, w2, pbuf);
    hipMemsetAsync(h2b, 0, (size_t)131072 * 64 * 2, stream);            // h1 dead; zero inactive h2b rows
    k_conv2c<<<157, 256, 0, stream>>>(list, pbuf, g2, b2, m2, v2, h2, h2b);
    k_impp<<<157 * 18, 256, 0, stream>>>(list, h2, wimp, pbuf);
    k_impc<<<157, 256, 0, stream>>>(pbuf, u_logits, kbits);
    k_select<<<2, 256, 0, stream>>>(u_logits, kth_u);
    k_dilate<<<157, 256, 0, stream>>>(list, u_logits, kbits, kth_u, new_act);
    k_zero<<<512, 256, 0, stream>>>(new_act, (float*)d_out);            // zero inactive rows only
    k_cnt<<<512, 256, 0, stream>>>(new_act, bcnt);                      // focal list (kbits dead now)
    k_scan<<<1, 512, 0, stream>>>(bcnt, boff, count);
    k_emit<<<512, 256, 0, stream>>>(new_act, boff, list);
    k_focal<<<2048, 256, 0, stream>>>(list, count, h2b, wfb, g3, b3, m3, v3,
                                      (float*)d_out, (const unsigned short*)zrow);
}

// Round 15
// 527.141 us; speedup vs baseline: 1.8315x; 1.0040x over previous
//
#include <hip/hip_runtime.h>
#include <stdint.h>

#define Dd 16
#define Hh 64
#define Ww 64
#define NACT 40000
#define NVb 20000
#define KFORE 10000
#define EPSf 0.001f

typedef __attribute__((ext_vector_type(8))) short short8;   // 8 bf16 (4 VGPR)
typedef __attribute__((ext_vector_type(4))) float f32x4;
typedef __attribute__((ext_vector_type(4))) unsigned short us4;

static __device__ __forceinline__ uint32_t f2sort(float f) {
    uint32_t u = __float_as_uint(f);
    return (u & 0x80000000u) ? ~u : (u | 0x80000000u);
}

// round-to-nearest-even f32 -> bf16 bits (inputs finite)
static __device__ __forceinline__ unsigned short f2b(float f) {
    uint32_t u = __float_as_uint(f);
    return (unsigned short)((u + 0x7FFFu + ((u >> 16) & 1u)) >> 16);
}

// bijective XCD-contiguous remap (m204)
static __device__ __forceinline__ int xcd_swz(int orig, int nwg) {
    int xcd = orig & 7, idx = orig >> 3;
    int q = nwg >> 3, r = nwg & 7;
    int base = xcd < r ? xcd * (q + 1) : r * (q + 1) + (xcd - r) * q;
    return base + idx;
}

// ---------------- scatter features to dense grid ----------------
__global__ void __launch_bounds__(256) k_scatter(const float* __restrict__ feat,
                                                 const int* __restrict__ coords,
                                                 float* __restrict__ dense16,
                                                 uint8_t* __restrict__ active,
                                                 uint8_t* __restrict__ new_act) {
    int i = blockIdx.x * 256 + threadIdx.x;
    if (i >= NACT) return;
    int b = coords[i * 4 + 0], z = coords[i * 4 + 1], y = coords[i * 4 + 2], x = coords[i * 4 + 3];
    int pos = ((b * Dd + z) * Hh + y) * Ww + x;
    active[pos] = 1;
    new_act[pos] = 1;
    const float4* f4 = (const float4*)(feat + (size_t)i * 16);
    float4* d4 = (float4*)(dense16 + (size_t)pos * 16);
    d4[0] = f4[0]; d4[1] = f4[1]; d4[2] = f4[2]; d4[3] = f4[3];
}

// ---------------- parallel ordered compaction: count -> scan -> emit ----------------
__global__ void __launch_bounds__(256) k_cnt(const uint8_t* __restrict__ mask,
                                             int* __restrict__ bcnt) {
    __shared__ int s[256];
    const int i = blockIdx.x * 256 + threadIdx.x;
    s[threadIdx.x] = mask[i] ? 1 : 0;
    __syncthreads();
    for (int off = 128; off > 0; off >>= 1) {
        if (threadIdx.x < off) s[threadIdx.x] += s[threadIdx.x + off];
        __syncthreads();
    }
    if (threadIdx.x == 0) bcnt[blockIdx.x] = s[0];
}

__global__ void __launch_bounds__(512) k_scan(const int* __restrict__ bcnt,
                                              int* __restrict__ boff, int* __restrict__ count) {
    __shared__ int s[512];
    const int t = threadIdx.x;
    const int v0 = bcnt[t];
    s[t] = v0;
    __syncthreads();
    for (int off = 1; off < 512; off <<= 1) {
        int v = s[t];
        if (t >= off) v += s[t - off];
        __syncthreads();
        s[t] = v;
        __syncthreads();
    }
    boff[t] = s[t] - v0;           // exclusive prefix
    if (t == 511) *count = s[511];
}

__global__ void __launch_bounds__(256) k_emit(const uint8_t* __restrict__ mask,
                                              const int* __restrict__ boff,
                                              int* __restrict__ list) {
    __shared__ int s[256];
    const int i = blockIdx.x * 256 + threadIdx.x;
    const int pred = mask[i] ? 1 : 0;
    s[threadIdx.x] = pred;
    __syncthreads();
    for (int off = 1; off < 256; off <<= 1) {
        int v = s[threadIdx.x];
        if (threadIdx.x >= off) v += s[threadIdx.x - off];
        __syncthreads();
        s[threadIdx.x] = v;
        __syncthreads();
    }
    if (pred) list[boff[blockIdx.x] + s[threadIdx.x] - 1] = i;
}

// ---------------- conv1 parts: 3 tap-parts x 4 ch-groups (8 ch) -> partial[tp][c][i] ----------------
__global__ void __launch_bounds__(256) k_conv1p(const int* __restrict__ list,
        const float* __restrict__ dense16, const float* __restrict__ w1,
        float* __restrict__ pbuf) {
    const int gb = xcd_swz(blockIdx.x, 157 * 12);
    const int chunk = gb / 12, sub = gb % 12;
    const int tp = sub >> 2, cb = (sub & 3) * 8;
    const int i = chunk * 256 + threadIdx.x;
    if (i >= NACT) return;
    const int pos = list[i];
    const int z = (pos >> 12) & 15, y = (pos >> 6) & 63, x = pos & 63;
    float acc[8];
    #pragma unroll
    for (int c = 0; c < 8; ++c) acc[c] = 0.f;
    const int dz = tp - 1;
    if ((unsigned)(z + dz) < Dd) {
        for (int tt = 0; tt < 9; ++tt) {
            const int dy = tt / 3 - 1, dx = tt % 3 - 1;
            if (!((unsigned)(y + dy) < Hh && (unsigned)(x + dx) < Ww)) continue;
            const float* row = dense16 + (size_t)(pos + dz * 4096 + dy * 64 + dx) * 16;
            const float* wt = w1 + (tp * 9 + tt) * 512 + cb;
            #pragma unroll
            for (int k4 = 0; k4 < 4; ++k4) {
                float4 xv = *(const float4*)(row + k4 * 4);
                float xs[4] = {xv.x, xv.y, xv.z, xv.w};
                #pragma unroll
                for (int j = 0; j < 4; ++j)
                    #pragma unroll
                    for (int c = 0; c < 8; ++c)
                        acc[c] = fmaf(xs[j], wt[(k4 * 4 + j) * 32 + c], acc[c]);
            }
        }
    }
    #pragma unroll
    for (int c = 0; c < 8; ++c) pbuf[(size_t)(tp * 32 + cb + c) * NACT + i] = acc[c];
}

// ---------------- conv1 combine: sum 3 parts + BN + ReLU -> h1 ----------------
__global__ void __launch_bounds__(256) k_conv1c(const int* __restrict__ list,
        const float* __restrict__ pbuf,
        const float* __restrict__ g, const float* __restrict__ bta,
        const float* __restrict__ mu, const float* __restrict__ va,
        float* __restrict__ h1) {
    const int i = blockIdx.x * 256 + threadIdx.x;
    if (i >= NACT) return;
    const int pos = list[i];
    float res[32];
    #pragma unroll
    for (int c = 0; c < 32; ++c) {
        float s = pbuf[(size_t)c * NACT + i]
                + pbuf[(size_t)(32 + c) * NACT + i]
                + pbuf[(size_t)(64 + c) * NACT + i];
        const float sc = g[c] * (1.0f / sqrtf(va[c] + EPSf));
        res[c] = fmaxf(0.f, fmaf(s - mu[c], sc, bta[c]));
    }
    #pragma unroll
    for (int c4 = 0; c4 < 8; ++c4)
        *(float4*)(h1 + (size_t)pos * 32 + c4 * 4) = *(float4*)&res[c4 * 4];
}

// ---------------- conv2 parts: 3 tap-parts x 4 ch-groups (16 ch) -> partial[tp][c][i] ----------------
__global__ void __launch_bounds__(256) k_conv2p(const int* __restrict__ list,
        const float* __restrict__ h1, const float* __restrict__ w2,
        float* __restrict__ pbuf) {
    const int gb = xcd_swz(blockIdx.x, 157 * 12);
    const int chunk = gb / 12, sub = gb % 12;
    const int tp = sub >> 2, cb = (sub & 3) * 16;
    const int i = chunk * 256 + threadIdx.x;
    if (i >= NACT) return;
    const int pos = list[i];
    const int z = (pos >> 12) & 15, y = (pos >> 6) & 63, x = pos & 63;
    float acc[16];
    #pragma unroll
    for (int c = 0; c < 16; ++c) acc[c] = 0.f;
    const int dz = tp - 1;
    if ((unsigned)(z + dz) < Dd) {
        for (int tt = 0; tt < 9; ++tt) {
            const int dy = tt / 3 - 1, dx = tt % 3 - 1;
            if (!((unsigned)(y + dy) < Hh && (unsigned)(x + dx) < Ww)) continue;
            const float* row = h1 + (size_t)(pos + dz * 4096 + dy * 64 + dx) * 32;
            const float* wt = w2 + (tp * 9 + tt) * 2048 + cb;
            #pragma unroll
            for (int k4 = 0; k4 < 8; ++k4) {
                float4 xv = *(const float4*)(row + k4 * 4);
                float xs[4] = {xv.x, xv.y, xv.z, xv.w};
                #pragma unroll
                for (int j = 0; j < 4; ++j)
                    #pragma unroll
                    for (int c = 0; c < 16; ++c)
                        acc[c] = fmaf(xs[j], wt[(k4 * 4 + j) * 64 + c], acc[c]);
            }
        }
    }
    #pragma unroll
    for (int c = 0; c < 16; ++c) pbuf[(size_t)(tp * 64 + cb + c) * NACT + i] = acc[c];
}

// ---------------- conv2 combine: sum 3 tap-parts + BN + ReLU -> h2 (f32) + h2b (bf16) ----------------
__global__ void __launch_bounds__(256) k_conv2c(const int* __restrict__ list,
        const float* __restrict__ pbuf,
        const float* __restrict__ g, const float* __restrict__ bta,
        const float* __restrict__ mu, const float* __restrict__ va,
        float* __restrict__ h2, unsigned short* __restrict__ h2b) {
    const int i = blockIdx.x * 256 + threadIdx.x;
    if (i >= NACT) return;
    const int pos = list[i];
    float res[64];
    #pragma unroll
    for (int c = 0; c < 64; ++c) {
        float s = pbuf[(size_t)c * NACT + i]
                + pbuf[(size_t)(64 + c) * NACT + i]
                + pbuf[(size_t)(128 + c) * NACT + i];
        const float sc = g[c] * (1.0f / sqrtf(va[c] + EPSf));
        res[c] = fmaxf(0.f, fmaf(s - mu[c], sc, bta[c]));
    }
    #pragma unroll
    for (int c4 = 0; c4 < 16; ++c4)
        *(float4*)(h2 + (size_t)pos * 64 + c4 * 4) = *(float4*)&res[c4 * 4];
    #pragma unroll
    for (int c4 = 0; c4 < 16; ++c4) {
        us4 o = { f2b(res[c4 * 4]), f2b(res[c4 * 4 + 1]), f2b(res[c4 * 4 + 2]), f2b(res[c4 * 4 + 3]) };
        *(us4*)(h2b + (size_t)pos * 64 + c4 * 4) = o;
    }
}

// ---------------- imp parts: 9 tap-parts x 2 ch-halves -> partial[tp][c][i] ----------------
template<int CB, int NC>
static __device__ __forceinline__ void imp_part(int i, int pos, int tp,
        const float* __restrict__ h2, const float* __restrict__ wimp,
        float* __restrict__ pbuf) {
    const int z = (pos >> 12) & 15, y = (pos >> 6) & 63, x = pos & 63;
    float acc[NC];
    #pragma unroll
    for (int c = 0; c < NC; ++c) acc[c] = 0.f;
    for (int tt = 0; tt < 3; ++tt) {
        const int t = tp * 3 + tt;
        const int dz = t / 9 - 1, dy = (t / 3) % 3 - 1, dx = t % 3 - 1;
        if (!((unsigned)(z + dz) < Dd && (unsigned)(y + dy) < Hh && (unsigned)(x + dx) < Ww)) continue;
        const float* row = h2 + (size_t)(pos + dz * 4096 + dy * 64 + dx) * 64;
        const float* wt = wimp + t * 1728 + CB;
        #pragma unroll
        for (int k4 = 0; k4 < 16; ++k4) {
            float4 xv = *(const float4*)(row + k4 * 4);
            float xs[4] = {xv.x, xv.y, xv.z, xv.w};
            #pragma unroll
            for (int j = 0; j < 4; ++j)
                #pragma unroll
                for (int c = 0; c < NC; ++c)
                    acc[c] = fmaf(xs[j], wt[(k4 * 4 + j) * 27 + c], acc[c]);
        }
    }
    #pragma unroll
    for (int c = 0; c < NC; ++c) pbuf[(size_t)(tp * 27 + CB + c) * NACT + i] = acc[c];
}

__global__ void __launch_bounds__(256) k_impp(const int* __restrict__ list,
        const float* __restrict__ h2, const float* __restrict__ wimp,
        float* __restrict__ pbuf) {
    const int gb = xcd_swz(blockIdx.x, 157 * 18);
    const int chunk = gb / 18, sub = gb % 18;
    const int tp = sub >> 1;
    const int i = chunk * 256 + threadIdx.x;
    if (i >= NACT) return;
    const int pos = list[i];
    if (sub & 1) imp_part<14, 13>(i, pos, tp, h2, wimp, pbuf);
    else         imp_part<0, 14>(i, pos, tp, h2, wimp, pbuf);
}

// ---------------- imp combine: sum 9 parts -> kernel-mask bits + voxel logit ----------------
__global__ void __launch_bounds__(256) k_impc(const float* __restrict__ pbuf,
        uint32_t* __restrict__ u_logits, uint32_t* __restrict__ kbits) {
    const int i = blockIdx.x * 256 + threadIdx.x;
    if (i >= NACT) return;
    uint32_t bits = 0;
    float logit = 0.f;
    #pragma unroll
    for (int c = 0; c < 27; ++c) {
        float s = 0.f;
        #pragma unroll
        for (int tp = 0; tp < 9; ++tp)
            s += pbuf[(size_t)(tp * 27 + c) * NACT + i];
        if (c < 26) bits |= (s >= 0.f ? 1u : 0u) << c;
        else logit = s;
    }
    kbits[i] = bits;
    u_logits[i] = f2sort(logit);
}

// ---------------- exact kth-largest ----------------
__global__ void __launch_bounds__(256) k_select(const uint32_t* __restrict__ u_all,
                                                uint32_t* __restrict__ kth_u) {
    const int b = blockIdx.x;
    const uint32_t* u = u_all + (size_t)b * NVb;
    __shared__ int hist[256];
    __shared__ int s_d, s_above;
    uint32_t prefix = 0;
    int K = KFORE;
    for (int p = 3; p >= 0; --p) {
        hist[threadIdx.x] = 0;
        __syncthreads();
        const int sh = p * 8;
        for (int i = threadIdx.x; i < NVb; i += 256) {
            uint32_t ui = u[i];
            bool cand;
            if (p == 3) cand = true;
            else cand = ((ui >> (sh + 8)) == prefix);
            if (cand) atomicAdd(&hist[(ui >> sh) & 255], 1);
        }
        __syncthreads();
        if (threadIdx.x == 0) {
            int cum = 0, d = 255;
            for (; d >= 0; --d) { cum += hist[d]; if (cum >= K) break; }
            s_d = d; s_above = cum - hist[d];
        }
        __syncthreads();
        prefix = (prefix << 8) | (uint32_t)s_d;
        K -= s_above;
        __syncthreads();
    }
    if (threadIdx.x == 0) kth_u[b] = prefix;
}

// ---------------- dilation ----------------
__global__ void __launch_bounds__(256) k_dilate(const int* __restrict__ list,
                                                const uint32_t* __restrict__ u_logits,
                                                const uint32_t* __restrict__ kbits,
                                                const uint32_t* __restrict__ kth_u,
                                                uint8_t* __restrict__ new_act) {
    int i = blockIdx.x * 256 + threadIdx.x;
    if (i >= NACT) return;
    int pos = list[i];
    int b = pos >> 16;
    if (u_logits[i] < kth_u[b]) return;
    int z = (pos >> 12) & 15, y = (pos >> 6) & 63, x = pos & 63;
    uint32_t bits = kbits[i];
    while (bits) {
        int ch = __ffs(bits) - 1;
        bits &= bits - 1;
        int l = ch + (ch >= 13 ? 1 : 0);
        int oz = l / 9 - 1, oy = (l / 3) % 3 - 1, ox = l % 3 - 1;
        int tz = z + oz, ty = y + oy, tx = x + ox;
        if (tz >= 1 && tz < Dd && ty >= 1 && ty < Hh && tx >= 1 && tx < Ww)
            new_act[((b * Dd + tz) * Hh + ty) * Ww + tx] = 1;
    }
}

// ---------------- zero output rows NOT in new_act (replaces 67MB memset) ----------------
__global__ void __launch_bounds__(256) k_zero(const uint8_t* __restrict__ new_act,
                                              float* __restrict__ out) {
    const int pos = blockIdx.x * 256 + threadIdx.x;   // 512 blocks x 256 = 131072
    if (new_act[pos]) return;                          // will be fully written by k_focal
    float4 z = {0.f, 0.f, 0.f, 0.f};
    float4* o = (float4*)(out + (size_t)pos * 128);
    #pragma unroll
    for (int j = 0; j < 32; ++j) o[j] = z;
}

// ---------------- w_focal f32 [27][64][128] -> bf16 transposed [27][128][64] ----------------
__global__ void __launch_bounds__(256) k_wcvt(const float* __restrict__ wf,
                                              unsigned short* __restrict__ wfb) {
    int i = blockIdx.x * 256 + threadIdx.x;   // 221184 total
    int t = i >> 13, r = i & 8191, n = r >> 6, k = r & 63;
    wfb[i] = f2b(wf[(t * 64 + k) * 128 + n]);
}

// ---------------- focal conv 64->128 via bf16 MFMA ----------------
// 256 thr (4 waves), 64 voxels/block; wave wv owns 32 output ch (2 N-tiles).
// 3-buffer LDS rotation -> ONE barrier per tap (write target (t+2)%3 was last
// read at t-1; the barrier ending iter t-1 orders read-before-write).
// As XOR-swizzled (16B-slot ^ (row&7)) -> 0 bank conflicts (measured R8-R14).
// Gathers: depth-2 lead via alternating reg sets. Weights: 2-tap lead (wE/wO).
__global__ void __launch_bounds__(256, 4) k_focal(
        const int* __restrict__ list, const int* __restrict__ count,
        const unsigned short* __restrict__ h2b, const unsigned short* __restrict__ wfb,
        const float* __restrict__ g, const float* __restrict__ bta,
        const float* __restrict__ mu, const float* __restrict__ va,
        float* __restrict__ out, const unsigned short* __restrict__ zb) {
    __shared__ __align__(16) unsigned short As[3][64 * 64];  // swizzled, no pad
    __shared__ int s_pos[64];
    const int n = *count;
    const int i0 = xcd_swz(blockIdx.x, 2048) * 64;
    if (i0 >= n) return;
    const int tid = threadIdx.x;
    const int wv = tid >> 6, lane = tid & 63;
    if (tid < 64) { int idx = i0 + tid; s_pos[tid] = idx < n ? list[idx] : -1; }
    __syncthreads();
    const int v0 = tid >> 3, c8 = tid & 7, v1 = v0 + 32;   // each thread stages rows v0, v1
    const int p0 = s_pos[v0], p1 = s_pos[v1];
    const int z0 = (p0 >> 12) & 15, y0 = (p0 >> 6) & 63, x0 = p0 & 63;
    const int z1 = (p1 >> 12) & 15, y1 = (p1 >> 6) & 63, x1 = p1 & 63;
    const int wslot = (c8 ^ (v0 & 7)) << 3;                 // v1&7 == v0&7
    const int wa0 = v0 * 64 + wslot, wa1 = v1 * 64 + wslot;
    const int hi = lane >> 4, lo = lane & 15;
    const int cb = wv * 32;

    f32x4 acc[4][2];
    #pragma unroll
    for (int mi = 0; mi < 4; ++mi)
        #pragma unroll
        for (int ni = 0; ni < 2; ++ni) acc[mi][ni] = (f32x4){0.f, 0.f, 0.f, 0.f};

    auto gather = [&](int t, short8& r0, short8& r1) {
        int dz = t / 9 - 1, dy = (t / 3) % 3 - 1, dx = t % 3 - 1;
        int off = dz * 4096 + dy * 64 + dx;
        bool ok0 = p0 >= 0 && (unsigned)(z0 + dz) < Dd && (unsigned)(y0 + dy) < Hh && (unsigned)(x0 + dx) < Ww;
        bool ok1 = p1 >= 0 && (unsigned)(z1 + dz) < Dd && (unsigned)(y1 + dy) < Hh && (unsigned)(x1 + dx) < Ww;
        r0 = *(const short8*)(ok0 ? h2b + (size_t)(p0 + off) * 64 + c8 * 8 : zb);
        r1 = *(const short8*)(ok1 ? h2b + (size_t)(p1 + off) * 64 + c8 * 8 : zb);
    };

    auto load_w = [&](int t, short8 (&w)[2][2]) {
        #pragma unroll
        for (int ni = 0; ni < 2; ++ni)
            #pragma unroll
            for (int ks = 0; ks < 2; ++ks)
                w[ni][ks] = *(const short8*)(wfb + (size_t)t * 8192
                                + (size_t)(cb + ni * 16 + lo) * 64 + ks * 32 + hi * 8);
    };

    auto compute = [&](int buf, const short8 (&w)[2][2]) {
        #pragma unroll
        for (int ks = 0; ks < 2; ++ks) {
            const int rs = ((ks * 4 + hi) ^ (lo & 7)) << 3;
            short8 a[4];
            #pragma unroll
            for (int mi = 0; mi < 4; ++mi)
                a[mi] = *(const short8*)&As[buf][(mi * 16 + lo) * 64 + rs];
            #pragma unroll
            for (int mi = 0; mi < 4; ++mi)
                #pragma unroll
                for (int ni = 0; ni < 2; ++ni)
                    acc[mi][ni] = __builtin_amdgcn_mfma_f32_16x16x32_bf16(
                        a[mi], w[ni][ks], acc[mi][ni], 0, 0, 0);
        }
    };

    short8 rA0, rA1, rB0, rB1;
    short8 wE[2][2], wO[2][2];
    // prologue: taps 0,1 -> LDS bufs 0,1; gathers for taps 2,3 in flight; weights 0,1 in regs
    gather(0, rA0, rA1);
    gather(1, rB0, rB1);
    *(short8*)&As[0][wa0] = rA0; *(short8*)&As[0][wa1] = rA1;
    *(short8*)&As[1][wa0] = rB0; *(short8*)&As[1][wa1] = rB1;
    gather(2, rA0, rA1);
    gather(3, rB0, rB1);
    load_w(0, wE);
    load_w(1, wO);
    __syncthreads();

    // main loop: ONE barrier per tap. Unrolled x2 so reg sets / weight sets are static.
    for (int t = 0; t < 27; t += 2) {
        // --- even tap t: compute buf t%3, write buf (t+2)%3 = rA, gather(t+4)->rA
        compute(t % 3, wE);
        if (t + 2 < 27) load_w(t + 2, wE);
        if (t + 2 < 27) {
            *(short8*)&As[(t + 2) % 3][wa0] = rA0;
            *(short8*)&As[(t + 2) % 3][wa1] = rA1;
            if (t + 4 < 27) gather(t + 4, rA0, rA1);
        }
        __syncthreads();
        if (t + 1 >= 27) break;
        // --- odd tap t+1: compute buf (t+1)%3, write buf (t+3)%3 = rB, gather(t+5)->rB
        compute((t + 1) % 3, wO);
        if (t + 3 < 27) load_w(t + 3, wO);
        if (t + 3 < 27) {
            *(short8*)&As[(t + 3) % 3][wa0] = rB0;
            *(short8*)&As[(t + 3) % 3][wa1] = rB1;
            if (t + 5 < 27) gather(t + 5, rB0, rB1);
        }
        __syncthreads();
    }

    #pragma unroll
    for (int ni = 0; ni < 2; ++ni) {
        const int ch = cb + ni * 16 + lo;
        const float s = g[ch] * (1.0f / sqrtf(va[ch] + EPSf));
        const float sh = bta[ch], mm = mu[ch];
        #pragma unroll
        for (int mi = 0; mi < 4; ++mi)
            #pragma unroll
            for (int j = 0; j < 4; ++j) {
                int vi = mi * 16 + hi * 4 + j;
                if (i0 + vi < n)
                    out[(size_t)s_pos[vi] * 128 + ch] = fmaxf(0.f, fmaf(acc[mi][ni][j] - mm, s, sh));
            }
    }
}

extern "C" void kernel_launch(void* const* d_in, const int* in_sizes, int n_in,
                              void* d_out, int out_size, void* d_ws, size_t ws_size,
                              hipStream_t stream) {
    (void)in_sizes; (void)n_in; (void)ws_size; (void)out_size;
    const float* feat   = (const float*)d_in[0];
    const int*   coords = (const int*)d_in[1];
    const float* w1   = (const float*)d_in[2];
    const float* w2   = (const float*)d_in[3];
    const float* wimp = (const float*)d_in[4];
    const float* wf   = (const float*)d_in[5];
    const float* g1 = (const float*)d_in[6],  *b1 = (const float*)d_in[7];
    const float* m1 = (const float*)d_in[8],  *v1 = (const float*)d_in[9];
    const float* g2 = (const float*)d_in[10], *b2 = (const float*)d_in[11];
    const float* m2 = (const float*)d_in[12], *v2 = (const float*)d_in[13];
    const float* g3 = (const float*)d_in[14], *b3 = (const float*)d_in[15];
    const float* m3 = (const float*)d_in[16], *v3 = (const float*)d_in[17];

    char* ws = (char*)d_ws;
    float*    dense16  = (float*)(ws + 0);           //  8,388,608 B (wfb overlays after conv1p)
    float*    h1       = (float*)(ws + 8388608);     // 16,777,216 B (h2b overlays after conv2p)
    float*    h2       = (float*)(ws + 25165824);    // 33,554,432 B
    uint8_t*  active   = (uint8_t*)(ws + 58720256);  //    131,072 B
    uint8_t*  new_act  = (uint8_t*)(ws + 58851328);  //    131,072 B
    float*    zrow     = (float*)(ws + 58982400);    //        256 B zeros
    int*      count    = (int*)(ws + 58982656);      //        256 B
    const size_t MEMSET_BYTES = 58982912;
    uint32_t* u_logits = (uint32_t*)(ws + 58982912); //    160,000 B
    uint32_t* kbits    = (uint32_t*)(ws + 59142912); //    160,000 B (also bcnt/boff scratch)
    uint32_t* kth_u    = (uint32_t*)(ws + 59302912); //        256 B
    int*      list     = (int*)(ws + 59303168);      //    524,288 B (act list, then focal list)

    unsigned short* wfb = (unsigned short*)dense16;  // [27][128][64] bf16, after conv1p
    unsigned short* h2b = (unsigned short*)h1;       // [131072][64] bf16, after conv2p+memset
    float* pbuf = (float*)d_out;                     // partial-sum scratch (used BEFORE out is written)
    int* bcnt = (int*)kbits;                         // 512 ints (dead region at both compact times)
    int* boff = (int*)kbits + 512;                   // 512 ints

    hipMemsetAsync(d_ws, 0, MEMSET_BYTES, stream);

    k_scatter<<<157, 256, 0, stream>>>(feat, coords, dense16, active, new_act);
    k_cnt<<<512, 256, 0, stream>>>(active, bcnt);                       // ordered active list
    k_scan<<<1, 512, 0, stream>>>(bcnt, boff, count);
    k_emit<<<512, 256, 0, stream>>>(active, boff, list);
    k_conv1p<<<157 * 12, 256, 0, stream>>>(list, dense16, w1, pbuf);
    k_conv1c<<<157, 256, 0, stream>>>(list, pbuf, g1, b1, m1, v1, h1);
    k_wcvt<<<864, 256, 0, stream>>>(wf, wfb);                           // dense16 now dead
    k_conv2p<<<157 * 12, 256, 0, stream>>>(list, h1, w2, pbuf);
    hipMemsetAsync(h2b, 0, (size_t)131072 * 64 * 2, stream);            // h1 dead; zero inactive h2b rows
    k_conv2c<<<157, 256, 0, stream>>>(list, pbuf, g2, b2, m2, v2, h2, h2b);
    k_impp<<<157 * 18, 256, 0, stream>>>(list, h2, wimp, pbuf);
    k_impc<<<157, 256, 0, stream>>>(pbuf, u_logits, kbits);
    k_select<<<2, 256, 0, stream>>>(u_logits, kth_u);
    k_dilate<<<157, 256, 0, stream>>>(list, u_logits, kbits, kth_u, new_act);
    k_zero<<<512, 256, 0, stream>>>(new_act, (float*)d_out);            // zero inactive rows only
    k_cnt<<<512, 256, 0, stream>>>(new_act, bcnt);                      // focal list (kbits dead now)
    k_scan<<<1, 512, 0, stream>>>(bcnt, boff, count);
    k_emit<<<512, 256, 0, stream>>>(new_act, boff, list);
    k_focal<<<2048, 256, 0, stream>>>(list, count, h2b, wfb, g3, b3, m3, v3,
                                      (float*)d_out, (const unsigned short*)zrow);
}